// Round 6
// baseline (324.933 us; speedup 1.0000x reference)
//
#include <hip/hip_runtime.h>
#include <hip/hip_bf16.h>

typedef __attribute__((ext_vector_type(4))) float f32x4;
typedef __attribute__((ext_vector_type(8))) short bf16x8;

#define BB 4
#define C 256
#define N 4096
#define TS 32
#define EPSI 1e-5f

__device__ __forceinline__ unsigned short f2bf(float f) {
    unsigned int u = __builtin_bit_cast(unsigned int, f);
    u += 0x7fffu + ((u >> 16) & 1u);
    return (unsigned short)(u >> 16);
}

// async global->LDS, 16B per lane; LDS dest is uniform-base + linear per-lane offset.
__device__ __forceinline__ void stage16(const unsigned short* g, unsigned short* l) {
    __builtin_amdgcn_global_load_lds(
        (const __attribute__((address_space(1))) void*)g,
        (__attribute__((address_space(3))) void*)l, 16, 0, 0);
}

// ---------------- Kernel 1: BN stats -> scale/shift per channel ----------------
__global__ __launch_bounds__(256) void bn_stats_k(
    const float* __restrict__ x, const float* __restrict__ gamma,
    const float* __restrict__ beta, float* __restrict__ scale, float* __restrict__ shift)
{
    int c = blockIdx.x;
    int tid = threadIdx.x;
    float s = 0.f, s2 = 0.f;
    for (int b = 0; b < BB; ++b) {
        const float4* p = (const float4*)(x + ((size_t)b * C + c) * N);
        for (int i = tid; i < N / 4; i += 256) {
            float4 v = p[i];
            s  += v.x + v.y + v.z + v.w;
            s2 += v.x * v.x + v.y * v.y + v.z * v.z + v.w * v.w;
        }
    }
    for (int m = 1; m < 64; m <<= 1) {
        s  += __shfl_xor(s, m);
        s2 += __shfl_xor(s2, m);
    }
    __shared__ float rs[4], rs2[4];
    int w = tid >> 6;
    if ((tid & 63) == 0) { rs[w] = s; rs2[w] = s2; }
    __syncthreads();
    if (tid == 0) {
        float S  = rs[0] + rs[1] + rs[2] + rs[3];
        float S2 = rs2[0] + rs2[1] + rs2[2] + rs2[3];
        const float inv_n = 1.f / (BB * N);
        float mean = S * inv_n;
        float var  = S2 * inv_n - mean * mean;
        float sc = gamma[c] * rsqrtf(var + EPSI);
        scale[c] = sc;
        shift[c] = beta[c] - mean * sc;
    }
}

// ---------------- Kernel 2: fused BN-apply + QKV projection (bf16 MFMA) ----------------
__global__ __launch_bounds__(256) void qkv_gemm_k(
    const float* __restrict__ x, const float* __restrict__ Wqkv, const float* __restrict__ bqkv,
    const float* __restrict__ scale, const float* __restrict__ shift,
    unsigned short* __restrict__ q, unsigned short* __restrict__ kt, unsigned short* __restrict__ v)
{
    __shared__ unsigned short Alds[128 * 40];  // [t][c] transposed, padded 32->40
    __shared__ unsigned short Blds[64 * 40];   // [o][c]
    int tid = threadIdx.x;
    int b  = blockIdx.z;
    int T0 = blockIdx.y * 128;
    int O0 = blockIdx.x * 64;
    int lane = tid & 63;
    int w = tid >> 6;
    int wm = w >> 1, wn = w & 1;
    int g = lane >> 4, l15 = lane & 15;

    f32x4 acc[4][2];
    for (int i = 0; i < 4; ++i)
        for (int j = 0; j < 2; ++j) acc[i][j] = f32x4{0.f, 0.f, 0.f, 0.f};

    int a_c = tid >> 3;          // 0..31
    int a_t = (tid & 7) * 16;    // 0..112
    int b_o = tid >> 2;          // 0..63
    int b_c = (tid & 3) * 8;     // 0,8,16,24

    for (int c0 = 0; c0 < C; c0 += 32) {
        {
            int cg = c0 + a_c;
            const float4* xp = (const float4*)(x + ((size_t)b * C + cg) * N + T0 + a_t);
            float sc = scale[cg], sh = shift[cg];
            for (int j = 0; j < 4; ++j) {
                float4 vv = xp[j];
                int t = a_t + j * 4;
                Alds[(t + 0) * 40 + a_c] = f2bf(vv.x * sc + sh);
                Alds[(t + 1) * 40 + a_c] = f2bf(vv.y * sc + sh);
                Alds[(t + 2) * 40 + a_c] = f2bf(vv.z * sc + sh);
                Alds[(t + 3) * 40 + a_c] = f2bf(vv.w * sc + sh);
            }
        }
        {
            const float4* wp = (const float4*)(Wqkv + (size_t)(O0 + b_o) * C + c0 + b_c);
            float4 v0 = wp[0], v1 = wp[1];
            int base = b_o * 40 + b_c;
            Blds[base + 0] = f2bf(v0.x); Blds[base + 1] = f2bf(v0.y);
            Blds[base + 2] = f2bf(v0.z); Blds[base + 3] = f2bf(v0.w);
            Blds[base + 4] = f2bf(v1.x); Blds[base + 5] = f2bf(v1.y);
            Blds[base + 6] = f2bf(v1.z); Blds[base + 7] = f2bf(v1.w);
        }
        __syncthreads();
        bf16x8 bfr[2];
        for (int nf = 0; nf < 2; ++nf)
            bfr[nf] = *(const bf16x8*)&Blds[(wn * 32 + nf * 16 + l15) * 40 + g * 8];
        for (int mf = 0; mf < 4; ++mf) {
            bf16x8 afr = *(const bf16x8*)&Alds[(wm * 64 + mf * 16 + l15) * 40 + g * 8];
            for (int nf = 0; nf < 2; ++nf)
                acc[mf][nf] = __builtin_amdgcn_mfma_f32_16x16x32_bf16(afr, bfr[nf], acc[mf][nf], 0, 0, 0);
        }
        __syncthreads();
    }
    for (int mf = 0; mf < 4; ++mf) {
        for (int nf = 0; nf < 2; ++nf) {
            int o = O0 + wn * 32 + nf * 16 + l15;
            float bias = bqkv[o];
            for (int r = 0; r < 4; ++r) {
                int t = T0 + wm * 64 + mf * 16 + g * 4 + r;
                float val = acc[mf][nf][r] + bias;
                if (O0 < 256) {
                    q[((size_t)b * N + t) * C + o] = f2bf(val * 0.0625f);   // fold 1/sqrt(256)
                } else if (O0 < 512) {
                    kt[((size_t)b * N + t) * C + (o - 256)] = f2bf(val);
                } else {
                    v[((size_t)b * C + (o - 512)) * N + t] = f2bf(val);     // transposed store
                }
            }
        }
    }
}

// ---------------- Kernel 3: flash attention ----------------
// 4 waves (256 thr, VGPR cap 256). Wave w: lw=w&1 -> Q rows [Q0+lw*32, +32),
// g2=w>>1 -> KV half. Each wave owns 32 Q rows as TWO 16-row fragment sets, so
// every K/V B-fragment read from LDS feeds 2 MFMAs (halves LDS read per Q-row).
// KV tiles of 32 double-buffered via global_load_lds (no staging VGPRs).
// Swizzle both-sides: linear LDS dest, inverse-XOR'd global source, same XOR on read.
__global__ __launch_bounds__(256) void attn_k(
    const unsigned short* __restrict__ q, const unsigned short* __restrict__ kt,
    const unsigned short* __restrict__ v, unsigned short* __restrict__ ao)
{
    __shared__ unsigned short Klds[2][2][TS * 256];   // [grp][buf][tk][c-chunks^] 64KB
    __shared__ unsigned short Vlds[2][2][256 * TS];   // [grp][buf][c][tk-chunks^] 64KB
    __shared__ unsigned short Plds[4][32 * TS];       // per-wave [qr][tk-chunks^]  8KB
    __shared__ float mlm[64], mll[64];

    int tid = threadIdx.x;
    int b  = blockIdx.y;
    int Q0 = blockIdx.x * 64;
    int lane = tid & 63;
    int w = tid >> 6;
    int lw = w & 1;        // Q sub-block (32 rows)
    int g2 = w >> 1;       // KV half
    int g = lane >> 4, l15 = lane & 15;
    int tg2 = tid & 127;   // thread index within staging group

    // Q fragments: 2 mreps x 8 k-chunks (64 VGPR)
    bf16x8 qf[2][8];
#pragma unroll
    for (int m = 0; m < 2; ++m) {
        const unsigned short* qp = q + ((size_t)b * N + Q0 + lw * 32 + m * 16 + l15) * C + g * 8;
#pragma unroll
        for (int kc = 0; kc < 8; ++kc)
            qf[m][kc] = *(const bf16x8*)(qp + kc * 32);
    }

    f32x4 oacc[2][16];
#pragma unroll
    for (int m = 0; m < 2; ++m)
#pragma unroll
        for (int i = 0; i < 16; ++i) oacc[m][i] = f32x4{0.f, 0.f, 0.f, 0.f};
    float mrow[2][4], lrow[2][4];
#pragma unroll
    for (int m = 0; m < 2; ++m)
#pragma unroll
        for (int r = 0; r < 4; ++r) { mrow[m][r] = -1e30f; lrow[m][r] = 0.f; }

    const unsigned short* kb = kt + ((size_t)b * N + g2 * 2048) * C;
    const unsigned short* vb = v + (size_t)b * C * N + g2 * 2048;

    // staging: per thread 8 K-chunks + 8 V-chunks of 16B (group = 128 threads)
    // K: qq=tg2+j*128: tk=qq>>5, slot=qq&31 holds global chunk slot^(tk&7)
    // V: qq=tg2+j*128: c=qq>>2,  slot=qq&3  holds global chunk slot^((c>>1)&3)
#define STAGE(buf_, t_)                                                              \
    {                                                                                \
        const unsigned short* kbt = kb + (size_t)(t_) * TS * 256;                    \
        _Pragma("unroll")                                                            \
        for (int j = 0; j < 8; ++j) {                                                \
            int qq = tg2 + j * 128;                                                  \
            int tk = qq >> 5, sc = qq & 31;                                          \
            stage16(kbt + tk * 256 + ((sc ^ (tk & 7)) * 8), &Klds[g2][buf_][qq * 8]);\
        }                                                                            \
        _Pragma("unroll")                                                            \
        for (int j = 0; j < 8; ++j) {                                                \
            int qq = tg2 + j * 128;                                                  \
            int c = qq >> 2, sl = qq & 3;                                            \
            stage16(vb + (size_t)c * N + (t_) * TS + ((sl ^ ((c >> 1) & 3)) * 8),    \
                    &Vlds[g2][buf_][qq * 8]);                                        \
        }                                                                            \
    }

    STAGE(0, 0);
    __syncthreads();   // drains vmcnt: tile 0 ready

    for (int t = 0; t < 64; ++t) {
        int cur = t & 1;
        if (t < 63) STAGE(cur ^ 1, t + 1);   // issue next tile; hides under compute

        // S = Q K^T : K-frag read once, used by both mreps
        f32x4 s[2][2];
#pragma unroll
        for (int m = 0; m < 2; ++m)
#pragma unroll
            for (int ct = 0; ct < 2; ++ct) s[m][ct] = f32x4{0.f, 0.f, 0.f, 0.f};
#pragma unroll
        for (int kc = 0; kc < 8; ++kc) {
#pragma unroll
            for (int ct = 0; ct < 2; ++ct) {
                int tk = ct * 16 + l15;
                int slot = (kc * 4 + g) ^ (tk & 7);
                bf16x8 kf = *(const bf16x8*)&Klds[g2][cur][tk * 256 + slot * 8];
                s[0][ct] = __builtin_amdgcn_mfma_f32_16x16x32_bf16(qf[0][kc], kf, s[0][ct], 0, 0, 0);
                s[1][ct] = __builtin_amdgcn_mfma_f32_16x16x32_bf16(qf[1][kc], kf, s[1][ct], 0, 0, 0);
            }
        }

        // online softmax (all 64 lanes active), 8 rows/lane-group
        float alpha[2][4];
#pragma unroll
        for (int m = 0; m < 2; ++m)
#pragma unroll
            for (int r = 0; r < 4; ++r) {
                float mx = fmaxf(s[m][0][r], s[m][1][r]);
                for (int off = 1; off < 16; off <<= 1) mx = fmaxf(mx, __shfl_xor(mx, off));
                float mn = fmaxf(mrow[m][r], mx);
                alpha[m][r] = __expf(mrow[m][r] - mn);
                mrow[m][r] = mn;
                float p0 = __expf(s[m][0][r] - mn);
                float p1 = __expf(s[m][1][r] - mn);
                s[m][0][r] = p0; s[m][1][r] = p1;
                float rs = p0 + p1;
                for (int off = 1; off < 16; off <<= 1) rs += __shfl_xor(rs, off);
                lrow[m][r] = lrow[m][r] * alpha[m][r] + rs;
            }
        bool nochg = true;
#pragma unroll
        for (int m = 0; m < 2; ++m)
#pragma unroll
            for (int r = 0; r < 4; ++r) nochg &= (alpha[m][r] == 1.f);
        if (!__all(nochg)) {
#pragma unroll
            for (int m = 0; m < 2; ++m)
#pragma unroll
                for (int f = 0; f < 16; ++f)
#pragma unroll
                    for (int r = 0; r < 4; ++r) oacc[m][f][r] *= alpha[m][r];
        }

        // P -> per-wave LDS (bf16, swizzled; rows 0..31)
#pragma unroll
        for (int m = 0; m < 2; ++m)
#pragma unroll
            for (int ct = 0; ct < 2; ++ct)
#pragma unroll
                for (int r = 0; r < 4; ++r) {
                    int row = m * 16 + g * 4 + r;
                    int lc = ct * 2 + (l15 >> 3);
                    int slot = lc ^ ((row >> 1) & 3);
                    Plds[w][row * TS + slot * 8 + (l15 & 7)] = f2bf(s[m][ct][r]);
                }

        // O += P V : V-frag read once, used by both mreps
        {
            int pslot = g ^ ((l15 >> 1) & 3);
            bf16x8 pf0 = *(const bf16x8*)&Plds[w][(l15) * TS + pslot * 8];
            bf16x8 pf1 = *(const bf16x8*)&Plds[w][(16 + l15) * TS + pslot * 8];
#pragma unroll
            for (int cf = 0; cf < 16; ++cf) {
                int c = cf * 16 + l15;
                int vslot = g ^ ((c >> 1) & 3);
                bf16x8 vf = *(const bf16x8*)&Vlds[g2][cur][c * TS + vslot * 8];
                oacc[0][cf] = __builtin_amdgcn_mfma_f32_16x16x32_bf16(pf0, vf, oacc[0][cf], 0, 0, 0);
                oacc[1][cf] = __builtin_amdgcn_mfma_f32_16x16x32_bf16(pf1, vf, oacc[1][cf], 0, 0, 0);
            }
        }
        __syncthreads();   // drains vmcnt: tile t+1 ready, buf cur free for t+2
    }

    // ---- epilogue: combine the two KV halves via LDS (reuse Klds as fp32 buffer) ----
    float* Ocomb = (float*)&Klds[0][0][0];   // 64 rows x 256 c fp32 = 64KB
    if (g2 == 1) {
#pragma unroll
        for (int m = 0; m < 2; ++m)
#pragma unroll
            for (int cf = 0; cf < 16; ++cf)
#pragma unroll
                for (int r = 0; r < 4; ++r)
                    Ocomb[(size_t)(lw * 32 + m * 16 + g * 4 + r) * 256 + cf * 16 + l15] = oacc[m][cf][r];
        if (l15 == 0) {
#pragma unroll
            for (int m = 0; m < 2; ++m)
#pragma unroll
                for (int r = 0; r < 4; ++r) {
                    int row = lw * 32 + m * 16 + g * 4 + r;
                    mlm[row] = mrow[m][r];
                    mll[row] = lrow[m][r];
                }
        }
    }
    __syncthreads();
    if (g2 == 0) {
        float w0[2][4], w1[2][4];
#pragma unroll
        for (int m = 0; m < 2; ++m)
#pragma unroll
            for (int r = 0; r < 4; ++r) {
                int row = lw * 32 + m * 16 + g * 4 + r;
                float m1 = mlm[row], l1 = mll[row];
                float mm = fmaxf(mrow[m][r], m1);
                float a0 = __expf(mrow[m][r] - mm), a1 = __expf(m1 - mm);
                float inv = 1.f / (a0 * lrow[m][r] + a1 * l1);
                w0[m][r] = a0 * inv;
                w1[m][r] = a1 * inv;
            }
#pragma unroll
        for (int m = 0; m < 2; ++m)
#pragma unroll
            for (int cf = 0; cf < 16; ++cf) {
                int c = cf * 16 + l15;
#pragma unroll
                for (int r = 0; r < 4; ++r) {
                    int row = lw * 32 + m * 16 + g * 4 + r;
                    float val = w0[m][r] * oacc[m][cf][r] + w1[m][r] * Ocomb[(size_t)row * 256 + c];
                    ao[((size_t)b * N + Q0 + row) * C + c] = f2bf(val);
                }
            }
    }
}

// ---------------- Kernel 4: out projection + bias + residual ----------------
__global__ __launch_bounds__(256) void out_gemm_k(
    const unsigned short* __restrict__ ao, const float* __restrict__ Wout,
    const float* __restrict__ bout, const float* __restrict__ x, float* __restrict__ out)
{
    __shared__ unsigned short Alds[64 * 72];
    __shared__ unsigned short Blds[128 * 72];
    int tid = threadIdx.x;
    int b   = blockIdx.z;
    int CO0 = blockIdx.y * 64;
    int T0  = blockIdx.x * 128;
    int lane = tid & 63;
    int w = tid >> 6;
    int wm = w >> 1, wn = w & 1;
    int g = lane >> 4, l15 = lane & 15;

    f32x4 acc[2][4];
    for (int i = 0; i < 2; ++i)
        for (int j = 0; j < 4; ++j) acc[i][j] = f32x4{0.f, 0.f, 0.f, 0.f};

    int a_r = tid >> 2;
    int a_cb = (tid & 3) * 16;

    for (int c0 = 0; c0 < C; c0 += 64) {
        {
            const float4* wp = (const float4*)(Wout + (size_t)(CO0 + a_r) * C + c0 + a_cb);
            for (int j = 0; j < 4; ++j) {
                float4 vv = wp[j];
                int base = a_r * 72 + a_cb + j * 4;
                Alds[base + 0] = f2bf(vv.x);
                Alds[base + 1] = f2bf(vv.y);
                Alds[base + 2] = f2bf(vv.z);
                Alds[base + 3] = f2bf(vv.w);
            }
        }
        for (int it = 0; it < 4; ++it) {
            int chunk = tid + it * 256;
            int tl = chunk >> 3, j = chunk & 7;
            *(bf16x8*)&Blds[tl * 72 + j * 8] =
                *(const bf16x8*)(ao + ((size_t)b * N + T0 + tl) * C + c0 + j * 8);
        }
        __syncthreads();
        for (int kk = 0; kk < 2; ++kk) {
            bf16x8 bfr[4];
            for (int nf = 0; nf < 4; ++nf)
                bfr[nf] = *(const bf16x8*)&Blds[(wn * 64 + nf * 16 + l15) * 72 + kk * 32 + g * 8];
            for (int mf = 0; mf < 2; ++mf) {
                bf16x8 afr = *(const bf16x8*)&Alds[(wm * 32 + mf * 16 + l15) * 72 + kk * 32 + g * 8];
                for (int nf = 0; nf < 4; ++nf)
                    acc[mf][nf] = __builtin_amdgcn_mfma_f32_16x16x32_bf16(afr, bfr[nf], acc[mf][nf], 0, 0, 0);
            }
        }
        __syncthreads();
    }
    for (int mf = 0; mf < 2; ++mf) {
        for (int nf = 0; nf < 4; ++nf) {
            int t = T0 + wn * 64 + nf * 16 + l15;
            for (int r = 0; r < 4; ++r) {
                int co = CO0 + wm * 32 + mf * 16 + g * 4 + r;
                size_t oidx = ((size_t)b * C + co) * N + t;
                out[oidx] = acc[mf][nf][r] + bout[co] + x[oidx];
            }
        }
    }
}

extern "C" void kernel_launch(void* const* d_in, const int* in_sizes, int n_in,
                              void* d_out, int out_size, void* d_ws, size_t ws_size,
                              hipStream_t stream) {
    const float* x     = (const float*)d_in[0];
    const float* Wqkv  = (const float*)d_in[1];
    const float* bqkv  = (const float*)d_in[2];
    const float* Wout  = (const float*)d_in[3];
    const float* bout  = (const float*)d_in[4];
    const float* gamma = (const float*)d_in[5];
    const float* beta  = (const float*)d_in[6];
    float* out = (float*)d_out;

    char* ws = (char*)d_ws;
    float* scale = (float*)ws;
    float* shift = (float*)(ws + 1024);
    unsigned short* q  = (unsigned short*)(ws + 4096);
    unsigned short* kt = q  + (size_t)BB * N * C;
    unsigned short* v  = kt + (size_t)BB * N * C;
    unsigned short* ao = v  + (size_t)BB * N * C;

    bn_stats_k<<<dim3(C), dim3(256), 0, stream>>>(x, gamma, beta, scale, shift);
    qkv_gemm_k<<<dim3(12, 32, BB), dim3(256), 0, stream>>>(x, Wqkv, bqkv, scale, shift, q, kt, v);
    attn_k<<<dim3(64, BB), dim3(256), 0, stream>>>(q, kt, v, ao);
    out_gemm_k<<<dim3(32, 4, BB), dim3(256), 0, stream>>>(ao, Wout, bout, x, out);
}

// Round 7
// 218.131 us; speedup vs baseline: 1.4896x; 1.4896x over previous
//
#include <hip/hip_runtime.h>
#include <hip/hip_bf16.h>

typedef __attribute__((ext_vector_type(4))) float f32x4;
typedef __attribute__((ext_vector_type(8))) short bf16x8;

#define BB 4
#define C 256
#define N 4096
#define TS 32
#define EPSI 1e-5f

__device__ __forceinline__ unsigned short f2bf(float f) {
    unsigned int u = __builtin_bit_cast(unsigned int, f);
    u += 0x7fffu + ((u >> 16) & 1u);
    return (unsigned short)(u >> 16);
}

// async global->LDS, 16B per lane; LDS dest is uniform-base + linear per-lane offset.
__device__ __forceinline__ void stage16(const unsigned short* g, unsigned short* l) {
    __builtin_amdgcn_global_load_lds(
        (const __attribute__((address_space(1))) void*)g,
        (__attribute__((address_space(3))) void*)l, 16, 0, 0);
}

// ---------------- Kernel 1: BN stats -> scale/shift per channel ----------------
__global__ __launch_bounds__(256) void bn_stats_k(
    const float* __restrict__ x, const float* __restrict__ gamma,
    const float* __restrict__ beta, float* __restrict__ scale, float* __restrict__ shift)
{
    int c = blockIdx.x;
    int tid = threadIdx.x;
    float s = 0.f, s2 = 0.f;
    for (int b = 0; b < BB; ++b) {
        const float4* p = (const float4*)(x + ((size_t)b * C + c) * N);
        for (int i = tid; i < N / 4; i += 256) {
            float4 v = p[i];
            s  += v.x + v.y + v.z + v.w;
            s2 += v.x * v.x + v.y * v.y + v.z * v.z + v.w * v.w;
        }
    }
    for (int m = 1; m < 64; m <<= 1) {
        s  += __shfl_xor(s, m);
        s2 += __shfl_xor(s2, m);
    }
    __shared__ float rs[4], rs2[4];
    int w = tid >> 6;
    if ((tid & 63) == 0) { rs[w] = s; rs2[w] = s2; }
    __syncthreads();
    if (tid == 0) {
        float S  = rs[0] + rs[1] + rs[2] + rs[3];
        float S2 = rs2[0] + rs2[1] + rs2[2] + rs2[3];
        const float inv_n = 1.f / (BB * N);
        float mean = S * inv_n;
        float var  = S2 * inv_n - mean * mean;
        float sc = gamma[c] * rsqrtf(var + EPSI);
        scale[c] = sc;
        shift[c] = beta[c] - mean * sc;
    }
}

// ---------------- Kernel 2: fused BN-apply + QKV projection (bf16 MFMA) ----------------
// Softmax scale folded into q as (1/16)*log2(e) so attention uses exp2.
__global__ __launch_bounds__(256) void qkv_gemm_k(
    const float* __restrict__ x, const float* __restrict__ Wqkv, const float* __restrict__ bqkv,
    const float* __restrict__ scale, const float* __restrict__ shift,
    unsigned short* __restrict__ q, unsigned short* __restrict__ kt, unsigned short* __restrict__ v)
{
    __shared__ unsigned short Alds[128 * 40];  // [t][c] transposed, padded 32->40
    __shared__ unsigned short Blds[64 * 40];   // [o][c]
    int tid = threadIdx.x;
    int b  = blockIdx.z;
    int T0 = blockIdx.y * 128;
    int O0 = blockIdx.x * 64;
    int lane = tid & 63;
    int w = tid >> 6;
    int wm = w >> 1, wn = w & 1;
    int g = lane >> 4, l15 = lane & 15;

    f32x4 acc[4][2];
    for (int i = 0; i < 4; ++i)
        for (int j = 0; j < 2; ++j) acc[i][j] = f32x4{0.f, 0.f, 0.f, 0.f};

    int a_c = tid >> 3;          // 0..31
    int a_t = (tid & 7) * 16;    // 0..112
    int b_o = tid >> 2;          // 0..63
    int b_c = (tid & 3) * 8;     // 0,8,16,24

    for (int c0 = 0; c0 < C; c0 += 32) {
        {
            int cg = c0 + a_c;
            const float4* xp = (const float4*)(x + ((size_t)b * C + cg) * N + T0 + a_t);
            float sc = scale[cg], sh = shift[cg];
            for (int j = 0; j < 4; ++j) {
                float4 vv = xp[j];
                int t = a_t + j * 4;
                Alds[(t + 0) * 40 + a_c] = f2bf(vv.x * sc + sh);
                Alds[(t + 1) * 40 + a_c] = f2bf(vv.y * sc + sh);
                Alds[(t + 2) * 40 + a_c] = f2bf(vv.z * sc + sh);
                Alds[(t + 3) * 40 + a_c] = f2bf(vv.w * sc + sh);
            }
        }
        {
            const float4* wp = (const float4*)(Wqkv + (size_t)(O0 + b_o) * C + c0 + b_c);
            float4 v0 = wp[0], v1 = wp[1];
            int base = b_o * 40 + b_c;
            Blds[base + 0] = f2bf(v0.x); Blds[base + 1] = f2bf(v0.y);
            Blds[base + 2] = f2bf(v0.z); Blds[base + 3] = f2bf(v0.w);
            Blds[base + 4] = f2bf(v1.x); Blds[base + 5] = f2bf(v1.y);
            Blds[base + 6] = f2bf(v1.z); Blds[base + 7] = f2bf(v1.w);
        }
        __syncthreads();
        bf16x8 bfr[2];
        for (int nf = 0; nf < 2; ++nf)
            bfr[nf] = *(const bf16x8*)&Blds[(wn * 32 + nf * 16 + l15) * 40 + g * 8];
        for (int mf = 0; mf < 4; ++mf) {
            bf16x8 afr = *(const bf16x8*)&Alds[(wm * 64 + mf * 16 + l15) * 40 + g * 8];
            for (int nf = 0; nf < 2; ++nf)
                acc[mf][nf] = __builtin_amdgcn_mfma_f32_16x16x32_bf16(afr, bfr[nf], acc[mf][nf], 0, 0, 0);
        }
        __syncthreads();
    }
    const float QSCALE = 0.0625f * 1.44269504088896f;   // (1/sqrt(256)) * log2(e)
    for (int mf = 0; mf < 4; ++mf) {
        for (int nf = 0; nf < 2; ++nf) {
            int o = O0 + wn * 32 + nf * 16 + l15;
            float bias = bqkv[o];
            for (int r = 0; r < 4; ++r) {
                int t = T0 + wm * 64 + mf * 16 + g * 4 + r;
                float val = acc[mf][nf][r] + bias;
                if (O0 < 256) {
                    q[((size_t)b * N + t) * C + o] = f2bf(val * QSCALE);
                } else if (O0 < 512) {
                    kt[((size_t)b * N + t) * C + (o - 256)] = f2bf(val);
                } else {
                    v[((size_t)b * C + (o - 512)) * N + t] = f2bf(val);     // transposed store
                }
            }
        }
    }
}

// ---------------- Kernel 3: flash attention (swapped-QK^T, per-lane softmax) ----
// 8 waves (512 thr), waves 0-3: KV[0,2048), waves 4-7: KV[2048,4096).
// QK^T computed SWAPPED: S^T = mfma(kf, qf) -> each lane owns ONE q-row
// (col = lane&15), so row max/sum are in-lane + 2 shfl_xor, and the O-rescale
// is a single scalar per lane. PV: O^T = mfma(vf, pf). Same LDS layout/staging
// as the 92-VGPR R5 kernel (global_load_lds dbuf, both-sides XOR swizzle).
__global__ __launch_bounds__(512) void attn_k(
    const unsigned short* __restrict__ q, const unsigned short* __restrict__ kt,
    const unsigned short* __restrict__ v, unsigned short* __restrict__ ao)
{
    __shared__ unsigned short Klds[2][2][TS * 256];   // [grp][buf][tk][c-chunks^] 64KB
    __shared__ unsigned short Vlds[2][2][256 * TS];   // [grp][buf][c][tk-chunks^] 64KB
    __shared__ unsigned short Plds[8][16 * TS];       // per-wave [q-row][tok-chunks^] 8KB
    __shared__ float mlm[64], mll[64];

    int tid = threadIdx.x;
    int b  = blockIdx.y;
    int Q0 = blockIdx.x * 64;
    int lane = tid & 63;
    int w = tid >> 6;
    int lw = w & 3;        // wave's Q-row block (16 rows)
    int g2 = w >> 2;       // KV half
    int g = lane >> 4, l15 = lane & 15;
    int tg = tid & 255;    // thread index within staging group

    // Q fragments (32 VGPR): lane l15 = q-row, chunk g*8 (+kc*32)
    bf16x8 qf[8];
    {
        const unsigned short* qp = q + ((size_t)b * N + Q0 + lw * 16 + l15) * C + g * 8;
#pragma unroll
        for (int kc = 0; kc < 8; ++kc)
            qf[kc] = *(const bf16x8*)(qp + kc * 32);
    }

    // O^T accumulator: oacc[cf][r] = O[q=l15][c = cf*16 + g*4 + r]
    f32x4 oacc[16];
#pragma unroll
    for (int i = 0; i < 16; ++i) oacc[i] = f32x4{0.f, 0.f, 0.f, 0.f};
    float mrow = -1e30f, lrow = 0.f;   // per-lane (q = l15), log2 domain

    const unsigned short* kb = kt + ((size_t)b * N + g2 * 2048) * C;
    const unsigned short* vb = v + (size_t)b * C * N + g2 * 2048;

#define STAGE(buf_, t_)                                                              \
    {                                                                                \
        const unsigned short* kbt = kb + (size_t)(t_) * TS * 256;                    \
        _Pragma("unroll")                                                            \
        for (int j = 0; j < 4; ++j) {                                                \
            int qq = tg + j * 256;                                                   \
            int tk = qq >> 5, sc = qq & 31;                                          \
            stage16(kbt + tk * 256 + ((sc ^ (tk & 7)) * 8), &Klds[g2][buf_][qq * 8]);\
        }                                                                            \
        _Pragma("unroll")                                                            \
        for (int j = 0; j < 4; ++j) {                                                \
            int qq = tg + j * 256;                                                   \
            int c = qq >> 2, sl = qq & 3;                                            \
            stage16(vb + (size_t)c * N + (t_) * TS + ((sl ^ ((c >> 1) & 3)) * 8),    \
                    &Vlds[g2][buf_][qq * 8]);                                        \
        }                                                                            \
    }

    STAGE(0, 0);
    __syncthreads();   // drains vmcnt: tile 0 ready

    for (int t = 0; t < 64; ++t) {
        int cur = t & 1;
        if (t < 63) STAGE(cur ^ 1, t + 1);   // issue next tile; hides under compute

        // S^T = K Q^T : st[ct] reg r holds S[q=l15][tok = ct*16 + g*4 + r]
        f32x4 st[2];
#pragma unroll
        for (int ct = 0; ct < 2; ++ct) st[ct] = f32x4{0.f, 0.f, 0.f, 0.f};
        __builtin_amdgcn_s_setprio(1);
#pragma unroll
        for (int kc = 0; kc < 8; ++kc) {
#pragma unroll
            for (int ct = 0; ct < 2; ++ct) {
                int tk = ct * 16 + l15;
                int slot = (kc * 4 + g) ^ (tk & 7);
                bf16x8 kf = *(const bf16x8*)&Klds[g2][cur][tk * 256 + slot * 8];
                st[ct] = __builtin_amdgcn_mfma_f32_16x16x32_bf16(kf, qf[kc], st[ct], 0, 0, 0);
            }
        }
        __builtin_amdgcn_s_setprio(0);

        // per-lane online softmax (lane owns q-row l15; 8 toks here, rest in g-peers)
        float mx = fmaxf(fmaxf(fmaxf(st[0][0], st[0][1]), fmaxf(st[0][2], st[0][3])),
                         fmaxf(fmaxf(st[1][0], st[1][1]), fmaxf(st[1][2], st[1][3])));
        mx = fmaxf(mx, __shfl_xor(mx, 16));
        mx = fmaxf(mx, __shfl_xor(mx, 32));
        float mn = fmaxf(mrow, mx);
        float alpha = exp2f(mrow - mn);
        mrow = mn;
        float rs = 0.f;
#pragma unroll
        for (int ct = 0; ct < 2; ++ct)
#pragma unroll
            for (int r = 0; r < 4; ++r) {
                float p = exp2f(st[ct][r] - mn);
                st[ct][r] = p;
                rs += p;
            }
        rs += __shfl_xor(rs, 16);
        rs += __shfl_xor(rs, 32);
        lrow = lrow * alpha + rs;
        if (!__all(alpha == 1.f)) {
#pragma unroll
            for (int f = 0; f < 16; ++f)
#pragma unroll
                for (int r = 0; r < 4; ++r) oacc[f][r] *= alpha;
        }

        // P -> per-wave LDS: row = q-row l15, tok = ct*16 + g*4 + r (swizzled slots)
#pragma unroll
        for (int ct = 0; ct < 2; ++ct)
#pragma unroll
            for (int r = 0; r < 4; ++r) {
                int lc = ct * 2 + (g >> 1);
                int slot = lc ^ ((l15 >> 1) & 3);
                Plds[w][l15 * TS + slot * 8 + (g & 1) * 4 + r] = f2bf(st[ct][r]);
            }

        // O^T += V^T P^T : pf = B-operand (col = q-row l15, toks chunk g*8)
        {
            int pslot = g ^ ((l15 >> 1) & 3);
            bf16x8 pf = *(const bf16x8*)&Plds[w][l15 * TS + pslot * 8];
            __builtin_amdgcn_s_setprio(1);
#pragma unroll
            for (int cf = 0; cf < 16; ++cf) {
                int c = cf * 16 + l15;
                int vslot = g ^ ((c >> 1) & 3);
                bf16x8 vf = *(const bf16x8*)&Vlds[g2][cur][c * TS + vslot * 8];
                oacc[cf] = __builtin_amdgcn_mfma_f32_16x16x32_bf16(vf, pf, oacc[cf], 0, 0, 0);
            }
            __builtin_amdgcn_s_setprio(0);
        }
        __syncthreads();   // drains vmcnt: tile t+1 ready, buf cur free for t+2
    }

    // ---- epilogue: combine the two KV halves via LDS (reuse Klds as fp32 buffer) ----
    float* Ocomb = (float*)&Klds[0][0][0];   // 64 rows x 256 c fp32 = 64KB
    int row = lw * 16 + l15;                 // this lane's q-row within the block
    if (g2 == 1) {
#pragma unroll
        for (int cf = 0; cf < 16; ++cf)
#pragma unroll
            for (int r = 0; r < 4; ++r)
                Ocomb[(size_t)row * 256 + cf * 16 + g * 4 + r] = oacc[cf][r];
        if (lane < 16) {
            mlm[row] = mrow;
            mll[row] = lrow;
        }
    }
    __syncthreads();
    if (g2 == 0) {
        float m1 = mlm[row], l1 = mll[row];
        float mm = fmaxf(mrow, m1);
        float a0 = exp2f(mrow - mm), a1 = exp2f(m1 - mm);
        float inv = 1.f / (a0 * lrow + a1 * l1);
        float w0 = a0 * inv, w1 = a1 * inv;
        unsigned short* aop = ao + ((size_t)b * N + Q0 + row) * C;
#pragma unroll
        for (int cf = 0; cf < 16; ++cf) {
#pragma unroll
            for (int rp = 0; rp < 2; ++rp) {
                int c = cf * 16 + g * 4 + rp * 2;
                float v0 = w0 * oacc[cf][rp * 2 + 0] + w1 * Ocomb[(size_t)row * 256 + c + 0];
                float v1 = w0 * oacc[cf][rp * 2 + 1] + w1 * Ocomb[(size_t)row * 256 + c + 1];
                unsigned int pk = (unsigned int)f2bf(v0) | ((unsigned int)f2bf(v1) << 16);
                *(unsigned int*)&aop[c] = pk;
            }
        }
    }
}

// ---------------- Kernel 4: out projection + bias + residual ----------------
__global__ __launch_bounds__(256) void out_gemm_k(
    const unsigned short* __restrict__ ao, const float* __restrict__ Wout,
    const float* __restrict__ bout, const float* __restrict__ x, float* __restrict__ out)
{
    __shared__ unsigned short Alds[64 * 72];
    __shared__ unsigned short Blds[128 * 72];
    int tid = threadIdx.x;
    int b   = blockIdx.z;
    int CO0 = blockIdx.y * 64;
    int T0  = blockIdx.x * 128;
    int lane = tid & 63;
    int w = tid >> 6;
    int wm = w >> 1, wn = w & 1;
    int g = lane >> 4, l15 = lane & 15;

    f32x4 acc[2][4];
    for (int i = 0; i < 2; ++i)
        for (int j = 0; j < 4; ++j) acc[i][j] = f32x4{0.f, 0.f, 0.f, 0.f};

    int a_r = tid >> 2;
    int a_cb = (tid & 3) * 16;

    for (int c0 = 0; c0 < C; c0 += 64) {
        {
            const float4* wp = (const float4*)(Wout + (size_t)(CO0 + a_r) * C + c0 + a_cb);
            for (int j = 0; j < 4; ++j) {
                float4 vv = wp[j];
                int base = a_r * 72 + a_cb + j * 4;
                Alds[base + 0] = f2bf(vv.x);
                Alds[base + 1] = f2bf(vv.y);
                Alds[base + 2] = f2bf(vv.z);
                Alds[base + 3] = f2bf(vv.w);
            }
        }
        for (int it = 0; it < 4; ++it) {
            int chunk = tid + it * 256;
            int tl = chunk >> 3, j = chunk & 7;
            *(bf16x8*)&Blds[tl * 72 + j * 8] =
                *(const bf16x8*)(ao + ((size_t)b * N + T0 + tl) * C + c0 + j * 8);
        }
        __syncthreads();
        for (int kk = 0; kk < 2; ++kk) {
            bf16x8 bfr[4];
            for (int nf = 0; nf < 4; ++nf)
                bfr[nf] = *(const bf16x8*)&Blds[(wn * 64 + nf * 16 + l15) * 72 + kk * 32 + g * 8];
            for (int mf = 0; mf < 2; ++mf) {
                bf16x8 afr = *(const bf16x8*)&Alds[(wm * 32 + mf * 16 + l15) * 72 + kk * 32 + g * 8];
                for (int nf = 0; nf < 4; ++nf)
                    acc[mf][nf] = __builtin_amdgcn_mfma_f32_16x16x32_bf16(afr, bfr[nf], acc[mf][nf], 0, 0, 0);
            }
        }
        __syncthreads();
    }
    for (int mf = 0; mf < 2; ++mf) {
        for (int nf = 0; nf < 4; ++nf) {
            int t = T0 + wn * 64 + nf * 16 + l15;
            for (int r = 0; r < 4; ++r) {
                int co = CO0 + wm * 32 + mf * 16 + g * 4 + r;
                size_t oidx = ((size_t)b * C + co) * N + t;
                out[oidx] = acc[mf][nf][r] + bout[co] + x[oidx];
            }
        }
    }
}

extern "C" void kernel_launch(void* const* d_in, const int* in_sizes, int n_in,
                              void* d_out, int out_size, void* d_ws, size_t ws_size,
                              hipStream_t stream) {
    const float* x     = (const float*)d_in[0];
    const float* Wqkv  = (const float*)d_in[1];
    const float* bqkv  = (const float*)d_in[2];
    const float* Wout  = (const float*)d_in[3];
    const float* bout  = (const float*)d_in[4];
    const float* gamma = (const float*)d_in[5];
    const float* beta  = (const float*)d_in[6];
    float* out = (float*)d_out;

    char* ws = (char*)d_ws;
    float* scale = (float*)ws;
    float* shift = (float*)(ws + 1024);
    unsigned short* q  = (unsigned short*)(ws + 4096);
    unsigned short* kt = q  + (size_t)BB * N * C;
    unsigned short* v  = kt + (size_t)BB * N * C;
    unsigned short* ao = v  + (size_t)BB * N * C;

    bn_stats_k<<<dim3(C), dim3(256), 0, stream>>>(x, gamma, beta, scale, shift);
    qkv_gemm_k<<<dim3(12, 32, BB), dim3(256), 0, stream>>>(x, Wqkv, bqkv, scale, shift, q, kt, v);
    attn_k<<<dim3(64, BB), dim3(512), 0, stream>>>(q, kt, v, ao);
    out_gemm_k<<<dim3(32, 4, BB), dim3(256), 0, stream>>>(ao, Wout, bout, x, out);
}

// Round 8
// 211.046 us; speedup vs baseline: 1.5396x; 1.0336x over previous
//
#include <hip/hip_runtime.h>
#include <hip/hip_bf16.h>

typedef __attribute__((ext_vector_type(4))) float f32x4;
typedef __attribute__((ext_vector_type(8))) short bf16x8;
typedef __attribute__((ext_vector_type(4))) unsigned int u32x4;

#define BB 4
#define C 256
#define N 4096
#define TS 32
#define EPSI 1e-5f

__device__ __forceinline__ unsigned short f2bf(float f) {
    unsigned int u = __builtin_bit_cast(unsigned int, f);
    u += 0x7fffu + ((u >> 16) & 1u);
    return (unsigned short)(u >> 16);
}

__device__ __forceinline__ unsigned int cvt_pk_bf16(float lo, float hi) {
    unsigned int r;
    asm("v_cvt_pk_bf16_f32 %0, %1, %2" : "=v"(r) : "v"(lo), "v"(hi));
    return r;
}

// async global->LDS, 16B per lane; LDS dest is uniform-base + linear per-lane offset.
__device__ __forceinline__ void stage16(const unsigned short* g, unsigned short* l) {
    __builtin_amdgcn_global_load_lds(
        (const __attribute__((address_space(1))) void*)g,
        (__attribute__((address_space(3))) void*)l, 16, 0, 0);
}

// ---------------- Kernel 1: BN stats -> scale/shift per channel ----------------
__global__ __launch_bounds__(256) void bn_stats_k(
    const float* __restrict__ x, const float* __restrict__ gamma,
    const float* __restrict__ beta, float* __restrict__ scale, float* __restrict__ shift)
{
    int c = blockIdx.x;
    int tid = threadIdx.x;
    float s = 0.f, s2 = 0.f;
    for (int b = 0; b < BB; ++b) {
        const float4* p = (const float4*)(x + ((size_t)b * C + c) * N);
        for (int i = tid; i < N / 4; i += 256) {
            float4 v = p[i];
            s  += v.x + v.y + v.z + v.w;
            s2 += v.x * v.x + v.y * v.y + v.z * v.z + v.w * v.w;
        }
    }
    for (int m = 1; m < 64; m <<= 1) {
        s  += __shfl_xor(s, m);
        s2 += __shfl_xor(s2, m);
    }
    __shared__ float rs[4], rs2[4];
    int w = tid >> 6;
    if ((tid & 63) == 0) { rs[w] = s; rs2[w] = s2; }
    __syncthreads();
    if (tid == 0) {
        float S  = rs[0] + rs[1] + rs[2] + rs[3];
        float S2 = rs2[0] + rs2[1] + rs2[2] + rs2[3];
        const float inv_n = 1.f / (BB * N);
        float mean = S * inv_n;
        float var  = S2 * inv_n - mean * mean;
        float sc = gamma[c] * rsqrtf(var + EPSI);
        scale[c] = sc;
        shift[c] = beta[c] - mean * sc;
    }
}

// ---------------- Kernel 2: fused BN-apply + QKV projection (bf16 MFMA) ----------------
// Softmax scale folded into q as (1/16)*log2(e) so attention uses exp2.
// V is stored with tokens PERMUTED within each 32-token group: tok at local gg*4+r
// goes to slot (gg&3)*2+(gg>>2), i.e. new local pos = ((g*2+(mf&1))*4 + r) below.
// This makes attn's PV V-fragment (k-reordered MFMA) a contiguous 16B LDS read.
__global__ __launch_bounds__(256) void qkv_gemm_k(
    const float* __restrict__ x, const float* __restrict__ Wqkv, const float* __restrict__ bqkv,
    const float* __restrict__ scale, const float* __restrict__ shift,
    unsigned short* __restrict__ q, unsigned short* __restrict__ kt, unsigned short* __restrict__ v)
{
    __shared__ unsigned short Alds[128 * 40];  // [t][c] transposed, padded 32->40
    __shared__ unsigned short Blds[64 * 40];   // [o][c]
    int tid = threadIdx.x;
    int b  = blockIdx.z;
    int T0 = blockIdx.y * 128;
    int O0 = blockIdx.x * 64;
    int lane = tid & 63;
    int w = tid >> 6;
    int wm = w >> 1, wn = w & 1;
    int g = lane >> 4, l15 = lane & 15;

    f32x4 acc[4][2];
    for (int i = 0; i < 4; ++i)
        for (int j = 0; j < 2; ++j) acc[i][j] = f32x4{0.f, 0.f, 0.f, 0.f};

    int a_c = tid >> 3;          // 0..31
    int a_t = (tid & 7) * 16;    // 0..112
    int b_o = tid >> 2;          // 0..63
    int b_c = (tid & 3) * 8;     // 0,8,16,24

    for (int c0 = 0; c0 < C; c0 += 32) {
        {
            int cg = c0 + a_c;
            const float4* xp = (const float4*)(x + ((size_t)b * C + cg) * N + T0 + a_t);
            float sc = scale[cg], sh = shift[cg];
            for (int j = 0; j < 4; ++j) {
                float4 vv = xp[j];
                int t = a_t + j * 4;
                Alds[(t + 0) * 40 + a_c] = f2bf(vv.x * sc + sh);
                Alds[(t + 1) * 40 + a_c] = f2bf(vv.y * sc + sh);
                Alds[(t + 2) * 40 + a_c] = f2bf(vv.z * sc + sh);
                Alds[(t + 3) * 40 + a_c] = f2bf(vv.w * sc + sh);
            }
        }
        {
            const float4* wp = (const float4*)(Wqkv + (size_t)(O0 + b_o) * C + c0 + b_c);
            float4 v0 = wp[0], v1 = wp[1];
            int base = b_o * 40 + b_c;
            Blds[base + 0] = f2bf(v0.x); Blds[base + 1] = f2bf(v0.y);
            Blds[base + 2] = f2bf(v0.z); Blds[base + 3] = f2bf(v0.w);
            Blds[base + 4] = f2bf(v1.x); Blds[base + 5] = f2bf(v1.y);
            Blds[base + 6] = f2bf(v1.z); Blds[base + 7] = f2bf(v1.w);
        }
        __syncthreads();
        bf16x8 bfr[2];
        for (int nf = 0; nf < 2; ++nf)
            bfr[nf] = *(const bf16x8*)&Blds[(wn * 32 + nf * 16 + l15) * 40 + g * 8];
        for (int mf = 0; mf < 4; ++mf) {
            bf16x8 afr = *(const bf16x8*)&Alds[(wm * 64 + mf * 16 + l15) * 40 + g * 8];
            for (int nf = 0; nf < 2; ++nf)
                acc[mf][nf] = __builtin_amdgcn_mfma_f32_16x16x32_bf16(afr, bfr[nf], acc[mf][nf], 0, 0, 0);
        }
        __syncthreads();
    }
    const float QSCALE = 0.0625f * 1.44269504088896f;   // (1/sqrt(256)) * log2(e)
    for (int mf = 0; mf < 4; ++mf) {
        for (int nf = 0; nf < 2; ++nf) {
            int o = O0 + wn * 32 + nf * 16 + l15;
            float bias = bqkv[o];
            for (int r = 0; r < 4; ++r) {
                int t = T0 + wm * 64 + mf * 16 + g * 4 + r;
                float val = acc[mf][nf][r] + bias;
                if (O0 < 256) {
                    q[((size_t)b * N + t) * C + o] = f2bf(val * QSCALE);
                } else if (O0 < 512) {
                    kt[((size_t)b * N + t) * C + (o - 256)] = f2bf(val);
                } else {
                    // permuted-token store for V (see header comment)
                    int tp = (t & ~31) | ((g * 2 + (mf & 1)) * 4 + r);
                    v[((size_t)b * C + (o - 512)) * N + tp] = f2bf(val);
                }
            }
        }
    }
}

// ---------------- Kernel 3: flash attention (swapped-QK^T, zero-shuffle PV) ----
// 8 waves (512 thr), waves 0-3: KV[0,2048), waves 4-7: KV[2048,4096).
// S^T = mfma(kf, qf): lane owns q-row l15. PV uses a k-REORDERED MFMA:
// k=g*8+j maps to tok=(j>>2)*16+g*4+(j&3), so P's B-fragment is the in-lane
// concat {st[0][0..3], st[1][0..3]} (4 cvt_pk, NO LDS round-trip); V's global
// layout is pre-permuted by kernel 2 so its A-fragment stays a contiguous read.
// T13 defer-max (THR=8, log2 domain) skips most max-updates/rescales.
__global__ __launch_bounds__(512) void attn_k(
    const unsigned short* __restrict__ q, const unsigned short* __restrict__ kt,
    const unsigned short* __restrict__ v, unsigned short* __restrict__ ao)
{
    __shared__ unsigned short Klds[2][2][TS * 256];   // [grp][buf][tk][c-chunks^] 64KB
    __shared__ unsigned short Vlds[2][2][256 * TS];   // [grp][buf][c][tok-slots]  64KB
    __shared__ float mlm[64], mll[64];

    int tid = threadIdx.x;
    int b  = blockIdx.y;
    int Q0 = blockIdx.x * 64;
    int lane = tid & 63;
    int w = tid >> 6;
    int lw = w & 3;        // wave's Q-row block (16 rows)
    int g2 = w >> 2;       // KV half
    int g = lane >> 4, l15 = lane & 15;
    int tg = tid & 255;    // thread index within staging group

    // Q fragments (32 VGPR): lane l15 = q-row, chunk g*8 (+kc*32)
    bf16x8 qf[8];
    {
        const unsigned short* qp = q + ((size_t)b * N + Q0 + lw * 16 + l15) * C + g * 8;
#pragma unroll
        for (int kc = 0; kc < 8; ++kc)
            qf[kc] = *(const bf16x8*)(qp + kc * 32);
    }

    // O^T accumulator: oacc[cf][r] = O[q=l15][c = cf*16 + g*4 + r]
    f32x4 oacc[16];
#pragma unroll
    for (int i = 0; i < 16; ++i) oacc[i] = f32x4{0.f, 0.f, 0.f, 0.f};
    float mrow = -1e30f, lrow = 0.f;   // per-lane (q = l15), log2 domain

    const unsigned short* kb = kt + ((size_t)b * N + g2 * 2048) * C;
    const unsigned short* vb = v + (size_t)b * C * N + g2 * 2048;

#define STAGE(buf_, t_)                                                              \
    {                                                                                \
        const unsigned short* kbt = kb + (size_t)(t_) * TS * 256;                    \
        _Pragma("unroll")                                                            \
        for (int j = 0; j < 4; ++j) {                                                \
            int qq = tg + j * 256;                                                   \
            int tk = qq >> 5, sc = qq & 31;                                          \
            stage16(kbt + tk * 256 + ((sc ^ (tk & 7)) * 8), &Klds[g2][buf_][qq * 8]);\
        }                                                                            \
        _Pragma("unroll")                                                            \
        for (int j = 0; j < 4; ++j) {                                                \
            int qq = tg + j * 256;                                                   \
            int c = qq >> 2, sl = qq & 3;                                            \
            stage16(vb + (size_t)c * N + (t_) * TS + ((sl ^ ((c >> 1) & 3)) * 8),    \
                    &Vlds[g2][buf_][qq * 8]);                                        \
        }                                                                            \
    }

    STAGE(0, 0);
    __syncthreads();   // drains vmcnt: tile 0 ready

    for (int t = 0; t < 64; ++t) {
        int cur = t & 1;
        if (t < 63) STAGE(cur ^ 1, t + 1);   // issue next tile; hides under compute

        // S^T = K Q^T : st[ct] reg r holds S[q=l15][tok = ct*16 + g*4 + r]
        f32x4 st[2];
#pragma unroll
        for (int ct = 0; ct < 2; ++ct) st[ct] = f32x4{0.f, 0.f, 0.f, 0.f};
        __builtin_amdgcn_s_setprio(1);
#pragma unroll
        for (int kc = 0; kc < 8; ++kc) {
#pragma unroll
            for (int ct = 0; ct < 2; ++ct) {
                int tk = ct * 16 + l15;
                int slot = (kc * 4 + g) ^ (tk & 7);
                bf16x8 kf = *(const bf16x8*)&Klds[g2][cur][tk * 256 + slot * 8];
                st[ct] = __builtin_amdgcn_mfma_f32_16x16x32_bf16(kf, qf[kc], st[ct], 0, 0, 0);
            }
        }
        __builtin_amdgcn_s_setprio(0);

        // per-lane online softmax with T13 defer-max (lane owns q-row l15)
        float mx = fmaxf(fmaxf(fmaxf(st[0][0], st[0][1]), fmaxf(st[0][2], st[0][3])),
                         fmaxf(fmaxf(st[1][0], st[1][1]), fmaxf(st[1][2], st[1][3])));
        mx = fmaxf(mx, __shfl_xor(mx, 16));
        mx = fmaxf(mx, __shfl_xor(mx, 32));
        if (!__all(mx - mrow <= 8.f)) {
            float mn = fmaxf(mrow, mx);
            float alpha = exp2f(mrow - mn);
            mrow = mn;
            lrow *= alpha;
#pragma unroll
            for (int f = 0; f < 16; ++f)
#pragma unroll
                for (int r = 0; r < 4; ++r) oacc[f][r] *= alpha;
        }
        float rs = 0.f;
#pragma unroll
        for (int ct = 0; ct < 2; ++ct)
#pragma unroll
            for (int r = 0; r < 4; ++r) {
                float p = exp2f(st[ct][r] - mrow);
                st[ct][r] = p;
                rs += p;
            }
        rs += __shfl_xor(rs, 16);
        rs += __shfl_xor(rs, 32);
        lrow += rs;

        // P B-fragment: in-lane pack (k = g*8+j -> tok=(j>>2)*16+g*4+(j&3))
        u32x4 pk;
        pk[0] = cvt_pk_bf16(st[0][0], st[0][1]);
        pk[1] = cvt_pk_bf16(st[0][2], st[0][3]);
        pk[2] = cvt_pk_bf16(st[1][0], st[1][1]);
        pk[3] = cvt_pk_bf16(st[1][2], st[1][3]);
        bf16x8 pf = __builtin_bit_cast(bf16x8, pk);

        // O^T += V P (k-reordered): vf chunk g*8 holds toks {g*4+r} u {16+g*4+r}
        __builtin_amdgcn_s_setprio(1);
#pragma unroll
        for (int cf = 0; cf < 16; ++cf) {
            int c = cf * 16 + l15;
            int vslot = g ^ ((c >> 1) & 3);
            bf16x8 vf = *(const bf16x8*)&Vlds[g2][cur][c * TS + vslot * 8];
            oacc[cf] = __builtin_amdgcn_mfma_f32_16x16x32_bf16(vf, pf, oacc[cf], 0, 0, 0);
        }
        __builtin_amdgcn_s_setprio(0);
        __syncthreads();   // drains vmcnt: tile t+1 ready, buf cur free for t+2
    }

    // ---- epilogue: combine the two KV halves via LDS (reuse Klds as fp32 buffer) ----
    float* Ocomb = (float*)&Klds[0][0][0];   // 64 rows x 256 c fp32 = 64KB
    int row = lw * 16 + l15;                 // this lane's q-row within the block
    if (g2 == 1) {
#pragma unroll
        for (int cf = 0; cf < 16; ++cf)
#pragma unroll
            for (int r = 0; r < 4; ++r)
                Ocomb[(size_t)row * 256 + cf * 16 + g * 4 + r] = oacc[cf][r];
        if (lane < 16) {
            mlm[row] = mrow;
            mll[row] = lrow;
        }
    }
    __syncthreads();
    if (g2 == 0) {
        float m1 = mlm[row], l1 = mll[row];
        float mm = fmaxf(mrow, m1);
        float a0 = exp2f(mrow - mm), a1 = exp2f(m1 - mm);
        float inv = 1.f / (a0 * lrow + a1 * l1);
        float w0 = a0 * inv, w1 = a1 * inv;
        unsigned short* aop = ao + ((size_t)b * N + Q0 + row) * C;
#pragma unroll
        for (int cf = 0; cf < 16; ++cf) {
#pragma unroll
            for (int rp = 0; rp < 2; ++rp) {
                int c = cf * 16 + g * 4 + rp * 2;
                float v0 = w0 * oacc[cf][rp * 2 + 0] + w1 * Ocomb[(size_t)row * 256 + c + 0];
                float v1 = w0 * oacc[cf][rp * 2 + 1] + w1 * Ocomb[(size_t)row * 256 + c + 1];
                unsigned int pk2 = (unsigned int)f2bf(v0) | ((unsigned int)f2bf(v1) << 16);
                *(unsigned int*)&aop[c] = pk2;
            }
        }
    }
}

// ---------------- Kernel 4: out projection + bias + residual ----------------
__global__ __launch_bounds__(256) void out_gemm_k(
    const unsigned short* __restrict__ ao, const float* __restrict__ Wout,
    const float* __restrict__ bout, const float* __restrict__ x, float* __restrict__ out)
{
    __shared__ unsigned short Alds[64 * 72];
    __shared__ unsigned short Blds[128 * 72];
    int tid = threadIdx.x;
    int b   = blockIdx.z;
    int CO0 = blockIdx.y * 64;
    int T0  = blockIdx.x * 128;
    int lane = tid & 63;
    int w = tid >> 6;
    int wm = w >> 1, wn = w & 1;
    int g = lane >> 4, l15 = lane & 15;

    f32x4 acc[2][4];
    for (int i = 0; i < 2; ++i)
        for (int j = 0; j < 4; ++j) acc[i][j] = f32x4{0.f, 0.f, 0.f, 0.f};

    int a_r = tid >> 2;
    int a_cb = (tid & 3) * 16;

    for (int c0 = 0; c0 < C; c0 += 64) {
        {
            const float4* wp = (const float4*)(Wout + (size_t)(CO0 + a_r) * C + c0 + a_cb);
            for (int j = 0; j < 4; ++j) {
                float4 vv = wp[j];
                int base = a_r * 72 + a_cb + j * 4;
                Alds[base + 0] = f2bf(vv.x);
                Alds[base + 1] = f2bf(vv.y);
                Alds[base + 2] = f2bf(vv.z);
                Alds[base + 3] = f2bf(vv.w);
            }
        }
        for (int it = 0; it < 4; ++it) {
            int chunk = tid + it * 256;
            int tl = chunk >> 3, j = chunk & 7;
            *(bf16x8*)&Blds[tl * 72 + j * 8] =
                *(const bf16x8*)(ao + ((size_t)b * N + T0 + tl) * C + c0 + j * 8);
        }
        __syncthreads();
        for (int kk = 0; kk < 2; ++kk) {
            bf16x8 bfr[4];
            for (int nf = 0; nf < 4; ++nf)
                bfr[nf] = *(const bf16x8*)&Blds[(wn * 64 + nf * 16 + l15) * 72 + kk * 32 + g * 8];
            for (int mf = 0; mf < 2; ++mf) {
                bf16x8 afr = *(const bf16x8*)&Alds[(wm * 32 + mf * 16 + l15) * 72 + kk * 32 + g * 8];
                for (int nf = 0; nf < 4; ++nf)
                    acc[mf][nf] = __builtin_amdgcn_mfma_f32_16x16x32_bf16(afr, bfr[nf], acc[mf][nf], 0, 0, 0);
            }
        }
        __syncthreads();
    }
    for (int mf = 0; mf < 2; ++mf) {
        for (int nf = 0; nf < 4; ++nf) {
            int t = T0 + wn * 64 + nf * 16 + l15;
            for (int r = 0; r < 4; ++r) {
                int co = CO0 + wm * 32 + mf * 16 + g * 4 + r;
                size_t oidx = ((size_t)b * C + co) * N + t;
                out[oidx] = acc[mf][nf][r] + bout[co] + x[oidx];
            }
        }
    }
}

extern "C" void kernel_launch(void* const* d_in, const int* in_sizes, int n_in,
                              void* d_out, int out_size, void* d_ws, size_t ws_size,
                              hipStream_t stream) {
    const float* x     = (const float*)d_in[0];
    const float* Wqkv  = (const float*)d_in[1];
    const float* bqkv  = (const float*)d_in[2];
    const float* Wout  = (const float*)d_in[3];
    const float* bout  = (const float*)d_in[4];
    const float* gamma = (const float*)d_in[5];
    const float* beta  = (const float*)d_in[6];
    float* out = (float*)d_out;

    char* ws = (char*)d_ws;
    float* scale = (float*)ws;
    float* shift = (float*)(ws + 1024);
    unsigned short* q  = (unsigned short*)(ws + 4096);
    unsigned short* kt = q  + (size_t)BB * N * C;
    unsigned short* v  = kt + (size_t)BB * N * C;
    unsigned short* ao = v  + (size_t)BB * N * C;

    bn_stats_k<<<dim3(C), dim3(256), 0, stream>>>(x, gamma, beta, scale, shift);
    qkv_gemm_k<<<dim3(12, 32, BB), dim3(256), 0, stream>>>(x, Wqkv, bqkv, scale, shift, q, kt, v);
    attn_k<<<dim3(64, BB), dim3(512), 0, stream>>>(q, kt, v, ao);
    out_gemm_k<<<dim3(32, 4, BB), dim3(256), 0, stream>>>(ao, Wout, bout, x, out);
}

// Round 9
// 193.359 us; speedup vs baseline: 1.6805x; 1.0915x over previous
//
#include <hip/hip_runtime.h>
#include <hip/hip_bf16.h>

typedef __attribute__((ext_vector_type(4))) float f32x4;
typedef __attribute__((ext_vector_type(8))) short bf16x8;
typedef __attribute__((ext_vector_type(4))) unsigned int u32x4;

#define BB 4
#define C 256
#define N 4096
#define TS 32
#define EPSI 1e-5f

__device__ __forceinline__ unsigned short f2bf(float f) {
    unsigned int u = __builtin_bit_cast(unsigned int, f);
    u += 0x7fffu + ((u >> 16) & 1u);
    return (unsigned short)(u >> 16);
}

__device__ __forceinline__ float bf2f(unsigned short h) {
    unsigned int u = ((unsigned int)h) << 16;
    return __builtin_bit_cast(float, u);
}

__device__ __forceinline__ unsigned int cvt_pk_bf16(float lo, float hi) {
    unsigned int r;
    asm("v_cvt_pk_bf16_f32 %0, %1, %2" : "=v"(r) : "v"(lo), "v"(hi));
    return r;
}

// async global->LDS, 16B per lane; LDS dest is uniform-base + linear per-lane offset.
__device__ __forceinline__ void stage16(const unsigned short* g, unsigned short* l) {
    __builtin_amdgcn_global_load_lds(
        (const __attribute__((address_space(1))) void*)g,
        (__attribute__((address_space(3))) void*)l, 16, 0, 0);
}

// ---------------- Kernel 1: BN stats -> scale/shift per channel ----------------
__global__ __launch_bounds__(256) void bn_stats_k(
    const float* __restrict__ x, const float* __restrict__ gamma,
    const float* __restrict__ beta, float* __restrict__ scale, float* __restrict__ shift)
{
    int c = blockIdx.x;
    int tid = threadIdx.x;
    float s = 0.f, s2 = 0.f;
    for (int b = 0; b < BB; ++b) {
        const float4* p = (const float4*)(x + ((size_t)b * C + c) * N);
        for (int i = tid; i < N / 4; i += 256) {
            float4 v = p[i];
            s  += v.x + v.y + v.z + v.w;
            s2 += v.x * v.x + v.y * v.y + v.z * v.z + v.w * v.w;
        }
    }
    for (int m = 1; m < 64; m <<= 1) {
        s  += __shfl_xor(s, m);
        s2 += __shfl_xor(s2, m);
    }
    __shared__ float rs[4], rs2[4];
    int w = tid >> 6;
    if ((tid & 63) == 0) { rs[w] = s; rs2[w] = s2; }
    __syncthreads();
    if (tid == 0) {
        float S  = rs[0] + rs[1] + rs[2] + rs[3];
        float S2 = rs2[0] + rs2[1] + rs2[2] + rs2[3];
        const float inv_n = 1.f / (BB * N);
        float mean = S * inv_n;
        float var  = S2 * inv_n - mean * mean;
        float sc = gamma[c] * rsqrtf(var + EPSI);
        scale[c] = sc;
        shift[c] = beta[c] - mean * sc;
    }
}

// ---------------- Kernel 2: fused BN-apply + QKV projection (bf16 MFMA) ----------------
// Softmax scale folded into q as (1/16)*log2(e) so attention uses exp2.
// V stored with tokens PERMUTED within each 32-token group (attn PV k-reorder).
__global__ __launch_bounds__(256) void qkv_gemm_k(
    const float* __restrict__ x, const float* __restrict__ Wqkv, const float* __restrict__ bqkv,
    const float* __restrict__ scale, const float* __restrict__ shift,
    unsigned short* __restrict__ q, unsigned short* __restrict__ kt, unsigned short* __restrict__ v)
{
    __shared__ unsigned short Alds[128 * 40];  // [t][c] transposed, padded 32->40
    __shared__ unsigned short Blds[64 * 40];   // [o][c]
    int tid = threadIdx.x;
    int b  = blockIdx.z;
    int T0 = blockIdx.y * 128;
    int O0 = blockIdx.x * 64;
    int lane = tid & 63;
    int w = tid >> 6;
    int wm = w >> 1, wn = w & 1;
    int g = lane >> 4, l15 = lane & 15;

    f32x4 acc[4][2];
    for (int i = 0; i < 4; ++i)
        for (int j = 0; j < 2; ++j) acc[i][j] = f32x4{0.f, 0.f, 0.f, 0.f};

    int a_c = tid >> 3;          // 0..31
    int a_t = (tid & 7) * 16;    // 0..112
    int b_o = tid >> 2;          // 0..63
    int b_c = (tid & 3) * 8;     // 0,8,16,24

    for (int c0 = 0; c0 < C; c0 += 32) {
        {
            int cg = c0 + a_c;
            const float4* xp = (const float4*)(x + ((size_t)b * C + cg) * N + T0 + a_t);
            float sc = scale[cg], sh = shift[cg];
            for (int j = 0; j < 4; ++j) {
                float4 vv = xp[j];
                int t = a_t + j * 4;
                Alds[(t + 0) * 40 + a_c] = f2bf(vv.x * sc + sh);
                Alds[(t + 1) * 40 + a_c] = f2bf(vv.y * sc + sh);
                Alds[(t + 2) * 40 + a_c] = f2bf(vv.z * sc + sh);
                Alds[(t + 3) * 40 + a_c] = f2bf(vv.w * sc + sh);
            }
        }
        {
            const float4* wp = (const float4*)(Wqkv + (size_t)(O0 + b_o) * C + c0 + b_c);
            float4 v0 = wp[0], v1 = wp[1];
            int base = b_o * 40 + b_c;
            Blds[base + 0] = f2bf(v0.x); Blds[base + 1] = f2bf(v0.y);
            Blds[base + 2] = f2bf(v0.z); Blds[base + 3] = f2bf(v0.w);
            Blds[base + 4] = f2bf(v1.x); Blds[base + 5] = f2bf(v1.y);
            Blds[base + 6] = f2bf(v1.z); Blds[base + 7] = f2bf(v1.w);
        }
        __syncthreads();
        bf16x8 bfr[2];
        for (int nf = 0; nf < 2; ++nf)
            bfr[nf] = *(const bf16x8*)&Blds[(wn * 32 + nf * 16 + l15) * 40 + g * 8];
        for (int mf = 0; mf < 4; ++mf) {
            bf16x8 afr = *(const bf16x8*)&Alds[(wm * 64 + mf * 16 + l15) * 40 + g * 8];
            for (int nf = 0; nf < 2; ++nf)
                acc[mf][nf] = __builtin_amdgcn_mfma_f32_16x16x32_bf16(afr, bfr[nf], acc[mf][nf], 0, 0, 0);
        }
        __syncthreads();
    }
    const float QSCALE = 0.0625f * 1.44269504088896f;   // (1/sqrt(256)) * log2(e)
    for (int mf = 0; mf < 4; ++mf) {
        for (int nf = 0; nf < 2; ++nf) {
            int o = O0 + wn * 32 + nf * 16 + l15;
            float bias = bqkv[o];
            for (int r = 0; r < 4; ++r) {
                int t = T0 + wm * 64 + mf * 16 + g * 4 + r;
                float val = acc[mf][nf][r] + bias;
                if (O0 < 256) {
                    q[((size_t)b * N + t) * C + o] = f2bf(val * QSCALE);
                } else if (O0 < 512) {
                    kt[((size_t)b * N + t) * C + (o - 256)] = f2bf(val);
                } else {
                    // permuted-token store for V (attn PV k-reorder)
                    int tp = (t & ~31) | ((g * 2 + (mf & 1)) * 4 + r);
                    v[((size_t)b * C + (o - 512)) * N + tp] = f2bf(val);
                }
            }
        }
    }
}

// ---------------- Kernel 3: flash attention (2 independent blocks/CU) ----------
// Grid (64 Qblk, 2 KV-half, BB). 256 thr = 4 waves, 64KB LDS -> 2 blocks/CU with
// INDEPENDENT barriers: co-resident blocks drift, so one block's softmax/barrier
// overlaps the other's MFMA/ds_read. Inner loop identical to R8 (swapped QK^T,
// zero-shuffle PV, defer-max). Writes unnormalized O-partial (bf16) + m,l;
// attn_combine_k merges the two halves.
__global__ __launch_bounds__(256) void attn_k(
    const unsigned short* __restrict__ q, const unsigned short* __restrict__ kt,
    const unsigned short* __restrict__ v,
    unsigned short* __restrict__ P0, unsigned short* __restrict__ P1,
    float* __restrict__ ml)
{
    __shared__ unsigned short Klds[2][TS * 256];   // dbuf [tk][c-chunks^] 32KB
    __shared__ unsigned short Vlds[2][256 * TS];   // dbuf [c][tok-slots]  32KB

    int tid = threadIdx.x;
    int h  = blockIdx.y;          // KV half
    int b  = blockIdx.z;
    int Q0 = blockIdx.x * 64;
    int lane = tid & 63;
    int lw = tid >> 6;            // wave = Q-row block (16 rows)
    int g = lane >> 4, l15 = lane & 15;

    // Q fragments (32 VGPR): lane l15 = q-row, chunk g*8 (+kc*32)
    bf16x8 qf[8];
    {
        const unsigned short* qp = q + ((size_t)b * N + Q0 + lw * 16 + l15) * C + g * 8;
#pragma unroll
        for (int kc = 0; kc < 8; ++kc)
            qf[kc] = *(const bf16x8*)(qp + kc * 32);
    }

    // O^T accumulator: oacc[cf][r] = O[q=l15][c = cf*16 + g*4 + r]
    f32x4 oacc[16];
#pragma unroll
    for (int i = 0; i < 16; ++i) oacc[i] = f32x4{0.f, 0.f, 0.f, 0.f};
    float mrow = -1e30f, lrow = 0.f;   // per-lane (q = l15), log2 domain

    const unsigned short* kb = kt + ((size_t)b * N + h * 2048) * C;
    const unsigned short* vb = v + (size_t)b * C * N + h * 2048;

#define STAGE(buf_, t_)                                                              \
    {                                                                                \
        const unsigned short* kbt = kb + (size_t)(t_) * TS * 256;                    \
        _Pragma("unroll")                                                            \
        for (int j = 0; j < 4; ++j) {                                                \
            int qq = tid + j * 256;                                                  \
            int tk = qq >> 5, sc = qq & 31;                                          \
            stage16(kbt + tk * 256 + ((sc ^ (tk & 7)) * 8), &Klds[buf_][qq * 8]);    \
        }                                                                            \
        _Pragma("unroll")                                                            \
        for (int j = 0; j < 4; ++j) {                                                \
            int qq = tid + j * 256;                                                  \
            int c = qq >> 2, sl = qq & 3;                                            \
            stage16(vb + (size_t)c * N + (t_) * TS + ((sl ^ ((c >> 1) & 3)) * 8),    \
                    &Vlds[buf_][qq * 8]);                                            \
        }                                                                            \
    }

    STAGE(0, 0);
    __syncthreads();   // drains vmcnt: tile 0 ready

    for (int t = 0; t < 64; ++t) {
        int cur = t & 1;
        if (t < 63) STAGE(cur ^ 1, t + 1);   // issue next tile; hides under compute

        // S^T = K Q^T : st[ct] reg r holds S[q=l15][tok = ct*16 + g*4 + r]
        f32x4 st[2];
#pragma unroll
        for (int ct = 0; ct < 2; ++ct) st[ct] = f32x4{0.f, 0.f, 0.f, 0.f};
        __builtin_amdgcn_s_setprio(1);
#pragma unroll
        for (int kc = 0; kc < 8; ++kc) {
#pragma unroll
            for (int ct = 0; ct < 2; ++ct) {
                int tk = ct * 16 + l15;
                int slot = (kc * 4 + g) ^ (tk & 7);
                bf16x8 kf = *(const bf16x8*)&Klds[cur][tk * 256 + slot * 8];
                st[ct] = __builtin_amdgcn_mfma_f32_16x16x32_bf16(kf, qf[kc], st[ct], 0, 0, 0);
            }
        }
        __builtin_amdgcn_s_setprio(0);

        // per-lane online softmax with defer-max (lane owns q-row l15)
        float mx = fmaxf(fmaxf(fmaxf(st[0][0], st[0][1]), fmaxf(st[0][2], st[0][3])),
                         fmaxf(fmaxf(st[1][0], st[1][1]), fmaxf(st[1][2], st[1][3])));
        mx = fmaxf(mx, __shfl_xor(mx, 16));
        mx = fmaxf(mx, __shfl_xor(mx, 32));
        if (!__all(mx - mrow <= 8.f)) {
            float mn = fmaxf(mrow, mx);
            float alpha = exp2f(mrow - mn);
            mrow = mn;
            lrow *= alpha;
#pragma unroll
            for (int f = 0; f < 16; ++f)
#pragma unroll
                for (int r = 0; r < 4; ++r) oacc[f][r] *= alpha;
        }
        float rs = 0.f;
#pragma unroll
        for (int ct = 0; ct < 2; ++ct)
#pragma unroll
            for (int r = 0; r < 4; ++r) {
                float p = exp2f(st[ct][r] - mrow);
                st[ct][r] = p;
                rs += p;
            }
        rs += __shfl_xor(rs, 16);
        rs += __shfl_xor(rs, 32);
        lrow += rs;

        // P B-fragment: in-lane pack (k = g*8+j -> tok=(j>>2)*16+g*4+(j&3))
        u32x4 pk;
        pk[0] = cvt_pk_bf16(st[0][0], st[0][1]);
        pk[1] = cvt_pk_bf16(st[0][2], st[0][3]);
        pk[2] = cvt_pk_bf16(st[1][0], st[1][1]);
        pk[3] = cvt_pk_bf16(st[1][2], st[1][3]);
        bf16x8 pf = __builtin_bit_cast(bf16x8, pk);

        // O^T += V P (k-reordered, V pre-permuted in global)
        __builtin_amdgcn_s_setprio(1);
#pragma unroll
        for (int cf = 0; cf < 16; ++cf) {
            int c = cf * 16 + l15;
            int vslot = g ^ ((c >> 1) & 3);
            bf16x8 vf = *(const bf16x8*)&Vlds[cur][c * TS + vslot * 8];
            oacc[cf] = __builtin_amdgcn_mfma_f32_16x16x32_bf16(vf, pf, oacc[cf], 0, 0, 0);
        }
        __builtin_amdgcn_s_setprio(0);
        __syncthreads();   // drains vmcnt: tile t+1 ready, buf cur free for t+2
    }

    // ---- epilogue: write unnormalized O-partial (bf16) + m,l ----
    {
        size_t tokid = (size_t)b * N + Q0 + lw * 16 + l15;
        if (g == 0) {
            ml[(size_t)(2 * h + 0) * (BB * N) + tokid] = mrow;
            ml[(size_t)(2 * h + 1) * (BB * N) + tokid] = lrow;
        }
        unsigned short* pp = (h == 0 ? P0 : P1) + tokid * C;
#pragma unroll
        for (int cf = 0; cf < 16; ++cf) {
#pragma unroll
            for (int rp = 0; rp < 2; ++rp) {
                int c = cf * 16 + g * 4 + rp * 2;
                unsigned int pk2 = cvt_pk_bf16(oacc[cf][rp * 2 + 0], oacc[cf][rp * 2 + 1]);
                *(unsigned int*)&pp[c] = pk2;
            }
        }
    }
}

// ---------------- Kernel 3b: combine the two KV-half partials ----------------
__global__ __launch_bounds__(256) void attn_combine_k(
    const unsigned short* __restrict__ P0, const unsigned short* __restrict__ P1,
    const float* __restrict__ ml, unsigned short* __restrict__ ao)
{
    int gid = blockIdx.x * 256 + threadIdx.x;   // chunk over BB*N*C/8
    int tok = gid >> 5;
    int ch8 = (gid & 31) * 8;
    float m0 = ml[tok],                  l0 = ml[(size_t)BB * N + tok];
    float m1 = ml[(size_t)2 * BB * N + tok], l1 = ml[(size_t)3 * BB * N + tok];
    float mm = fmaxf(m0, m1);
    float a0 = exp2f(m0 - mm), a1 = exp2f(m1 - mm);
    float inv = 1.f / (a0 * l0 + a1 * l1);
    float w0 = a0 * inv, w1 = a1 * inv;
    size_t base = (size_t)tok * C + ch8;
    bf16x8 p0 = *(const bf16x8*)(P0 + base);
    bf16x8 p1 = *(const bf16x8*)(P1 + base);
    unsigned int opk[4];
#pragma unroll
    for (int j = 0; j < 4; ++j) {
        float v0 = w0 * bf2f((unsigned short)p0[2 * j + 0]) + w1 * bf2f((unsigned short)p1[2 * j + 0]);
        float v1 = w0 * bf2f((unsigned short)p0[2 * j + 1]) + w1 * bf2f((unsigned short)p1[2 * j + 1]);
        opk[j] = cvt_pk_bf16(v0, v1);
    }
    *(u32x4*)(ao + base) = *(u32x4*)opk;
}

// ---------------- Kernel 4: out projection + bias + residual ----------------
__global__ __launch_bounds__(256) void out_gemm_k(
    const unsigned short* __restrict__ ao, const float* __restrict__ Wout,
    const float* __restrict__ bout, const float* __restrict__ x, float* __restrict__ out)
{
    __shared__ unsigned short Alds[64 * 72];
    __shared__ unsigned short Blds[128 * 72];
    int tid = threadIdx.x;
    int b   = blockIdx.z;
    int CO0 = blockIdx.y * 64;
    int T0  = blockIdx.x * 128;
    int lane = tid & 63;
    int w = tid >> 6;
    int wm = w >> 1, wn = w & 1;
    int g = lane >> 4, l15 = lane & 15;

    f32x4 acc[2][4];
    for (int i = 0; i < 2; ++i)
        for (int j = 0; j < 4; ++j) acc[i][j] = f32x4{0.f, 0.f, 0.f, 0.f};

    int a_r = tid >> 2;
    int a_cb = (tid & 3) * 16;

    for (int c0 = 0; c0 < C; c0 += 64) {
        {
            const float4* wp = (const float4*)(Wout + (size_t)(CO0 + a_r) * C + c0 + a_cb);
            for (int j = 0; j < 4; ++j) {
                float4 vv = wp[j];
                int base = a_r * 72 + a_cb + j * 4;
                Alds[base + 0] = f2bf(vv.x);
                Alds[base + 1] = f2bf(vv.y);
                Alds[base + 2] = f2bf(vv.z);
                Alds[base + 3] = f2bf(vv.w);
            }
        }
        for (int it = 0; it < 4; ++it) {
            int chunk = tid + it * 256;
            int tl = chunk >> 3, j = chunk & 7;
            *(bf16x8*)&Blds[tl * 72 + j * 8] =
                *(const bf16x8*)(ao + ((size_t)b * N + T0 + tl) * C + c0 + j * 8);
        }
        __syncthreads();
        for (int kk = 0; kk < 2; ++kk) {
            bf16x8 bfr[4];
            for (int nf = 0; nf < 4; ++nf)
                bfr[nf] = *(const bf16x8*)&Blds[(wn * 64 + nf * 16 + l15) * 72 + kk * 32 + g * 8];
            for (int mf = 0; mf < 2; ++mf) {
                bf16x8 afr = *(const bf16x8*)&Alds[(wm * 32 + mf * 16 + l15) * 72 + kk * 32 + g * 8];
                for (int nf = 0; nf < 4; ++nf)
                    acc[mf][nf] = __builtin_amdgcn_mfma_f32_16x16x32_bf16(afr, bfr[nf], acc[mf][nf], 0, 0, 0);
            }
        }
        __syncthreads();
    }
    for (int mf = 0; mf < 2; ++mf) {
        for (int nf = 0; nf < 4; ++nf) {
            int t = T0 + wn * 64 + nf * 16 + l15;
            for (int r = 0; r < 4; ++r) {
                int co = CO0 + wm * 32 + mf * 16 + g * 4 + r;
                size_t oidx = ((size_t)b * C + co) * N + t;
                out[oidx] = acc[mf][nf][r] + bout[co] + x[oidx];
            }
        }
    }
}

extern "C" void kernel_launch(void* const* d_in, const int* in_sizes, int n_in,
                              void* d_out, int out_size, void* d_ws, size_t ws_size,
                              hipStream_t stream) {
    const float* x     = (const float*)d_in[0];
    const float* Wqkv  = (const float*)d_in[1];
    const float* bqkv  = (const float*)d_in[2];
    const float* Wout  = (const float*)d_in[3];
    const float* bout  = (const float*)d_in[4];
    const float* gamma = (const float*)d_in[5];
    const float* beta  = (const float*)d_in[6];
    float* out = (float*)d_out;

    char* ws = (char*)d_ws;
    float* scale = (float*)ws;
    float* shift = (float*)(ws + 1024);
    unsigned short* q  = (unsigned short*)(ws + 4096);
    unsigned short* kt = q  + (size_t)BB * N * C;
    unsigned short* v  = kt + (size_t)BB * N * C;
    unsigned short* P0 = v  + (size_t)BB * N * C;
    unsigned short* P1 = P0 + (size_t)BB * N * C;
    float* ml = (float*)(P1 + (size_t)BB * N * C);   // 4 segments of BB*N f32

    bn_stats_k<<<dim3(C), dim3(256), 0, stream>>>(x, gamma, beta, scale, shift);
    qkv_gemm_k<<<dim3(12, 32, BB), dim3(256), 0, stream>>>(x, Wqkv, bqkv, scale, shift, q, kt, v);
    attn_k<<<dim3(64, 2, BB), dim3(256), 0, stream>>>(q, kt, v, P0, P1, ml);
    // combine writes final ao into the q buffer (q is fully rewritten by qkv next call)
    attn_combine_k<<<dim3(BB * N * C / 8 / 256), dim3(256), 0, stream>>>(P0, P1, ml, q);
    out_gemm_k<<<dim3(32, 4, BB), dim3(256), 0, stream>>>(q, Wout, bout, x, out);
}

// Round 10
// 171.058 us; speedup vs baseline: 1.8995x; 1.1304x over previous
//
#include <hip/hip_runtime.h>
#include <hip/hip_bf16.h>

typedef __attribute__((ext_vector_type(4))) float f32x4;
typedef __attribute__((ext_vector_type(8))) short bf16x8;
typedef __attribute__((ext_vector_type(4))) unsigned int u32x4;

#define BB 4
#define C 256
#define N 4096
#define TS 32
#define EPSI 1e-5f

__device__ __forceinline__ unsigned short f2bf(float f) {
    unsigned int u = __builtin_bit_cast(unsigned int, f);
    u += 0x7fffu + ((u >> 16) & 1u);
    return (unsigned short)(u >> 16);
}

__device__ __forceinline__ float bf2f(unsigned short h) {
    unsigned int u = ((unsigned int)h) << 16;
    return __builtin_bit_cast(float, u);
}

__device__ __forceinline__ unsigned int cvt_pk_bf16(float lo, float hi) {
    unsigned int r;
    asm("v_cvt_pk_bf16_f32 %0, %1, %2" : "=v"(r) : "v"(lo), "v"(hi));
    return r;
}

// async global->LDS, 16B per lane; LDS dest is uniform-base + linear per-lane offset.
__device__ __forceinline__ void stage16(const unsigned short* g, unsigned short* l) {
    __builtin_amdgcn_global_load_lds(
        (const __attribute__((address_space(1))) void*)g,
        (__attribute__((address_space(3))) void*)l, 16, 0, 0);
}

// ---------------- Kernel 1: BN stats -> scale/shift per channel ----------------
__global__ __launch_bounds__(256) void bn_stats_k(
    const float* __restrict__ x, const float* __restrict__ gamma,
    const float* __restrict__ beta, float* __restrict__ scale, float* __restrict__ shift)
{
    int c = blockIdx.x;
    int tid = threadIdx.x;
    float s = 0.f, s2 = 0.f;
    for (int b = 0; b < BB; ++b) {
        const float4* p = (const float4*)(x + ((size_t)b * C + c) * N);
        for (int i = tid; i < N / 4; i += 256) {
            float4 v = p[i];
            s  += v.x + v.y + v.z + v.w;
            s2 += v.x * v.x + v.y * v.y + v.z * v.z + v.w * v.w;
        }
    }
    for (int m = 1; m < 64; m <<= 1) {
        s  += __shfl_xor(s, m);
        s2 += __shfl_xor(s2, m);
    }
    __shared__ float rs[4], rs2[4];
    int w = tid >> 6;
    if ((tid & 63) == 0) { rs[w] = s; rs2[w] = s2; }
    __syncthreads();
    if (tid == 0) {
        float S  = rs[0] + rs[1] + rs[2] + rs[3];
        float S2 = rs2[0] + rs2[1] + rs2[2] + rs2[3];
        const float inv_n = 1.f / (BB * N);
        float mean = S * inv_n;
        float var  = S2 * inv_n - mean * mean;
        float sc = gamma[c] * rsqrtf(var + EPSI);
        scale[c] = sc;
        shift[c] = beta[c] - mean * sc;
    }
}

// ---------------- Kernel 2: fused BN-apply + QKV projection (bf16 MFMA) ----------------
// Softmax scale folded into q as (1/16)*log2(e) so attention uses exp2.
// V stored with tokens PERMUTED within each 32-token group (attn PV k-reorder).
__global__ __launch_bounds__(256) void qkv_gemm_k(
    const float* __restrict__ x, const float* __restrict__ Wqkv, const float* __restrict__ bqkv,
    const float* __restrict__ scale, const float* __restrict__ shift,
    unsigned short* __restrict__ q, unsigned short* __restrict__ kt, unsigned short* __restrict__ v)
{
    __shared__ unsigned short Alds[128 * 40];  // [t][c] transposed, padded 32->40
    __shared__ unsigned short Blds[64 * 40];   // [o][c]
    int tid = threadIdx.x;
    int b  = blockIdx.z;
    int T0 = blockIdx.y * 128;
    int O0 = blockIdx.x * 64;
    int lane = tid & 63;
    int w = tid >> 6;
    int wm = w >> 1, wn = w & 1;
    int g = lane >> 4, l15 = lane & 15;

    f32x4 acc[4][2];
    for (int i = 0; i < 4; ++i)
        for (int j = 0; j < 2; ++j) acc[i][j] = f32x4{0.f, 0.f, 0.f, 0.f};

    int a_c = tid >> 3;          // 0..31
    int a_t = (tid & 7) * 16;    // 0..112
    int b_o = tid >> 2;          // 0..63
    int b_c = (tid & 3) * 8;     // 0,8,16,24

    for (int c0 = 0; c0 < C; c0 += 32) {
        {
            int cg = c0 + a_c;
            const float4* xp = (const float4*)(x + ((size_t)b * C + cg) * N + T0 + a_t);
            float sc = scale[cg], sh = shift[cg];
            for (int j = 0; j < 4; ++j) {
                float4 vv = xp[j];
                int t = a_t + j * 4;
                Alds[(t + 0) * 40 + a_c] = f2bf(vv.x * sc + sh);
                Alds[(t + 1) * 40 + a_c] = f2bf(vv.y * sc + sh);
                Alds[(t + 2) * 40 + a_c] = f2bf(vv.z * sc + sh);
                Alds[(t + 3) * 40 + a_c] = f2bf(vv.w * sc + sh);
            }
        }
        {
            const float4* wp = (const float4*)(Wqkv + (size_t)(O0 + b_o) * C + c0 + b_c);
            float4 v0 = wp[0], v1 = wp[1];
            int base = b_o * 40 + b_c;
            Blds[base + 0] = f2bf(v0.x); Blds[base + 1] = f2bf(v0.y);
            Blds[base + 2] = f2bf(v0.z); Blds[base + 3] = f2bf(v0.w);
            Blds[base + 4] = f2bf(v1.x); Blds[base + 5] = f2bf(v1.y);
            Blds[base + 6] = f2bf(v1.z); Blds[base + 7] = f2bf(v1.w);
        }
        __syncthreads();
        bf16x8 bfr[2];
        for (int nf = 0; nf < 2; ++nf)
            bfr[nf] = *(const bf16x8*)&Blds[(wn * 32 + nf * 16 + l15) * 40 + g * 8];
        for (int mf = 0; mf < 4; ++mf) {
            bf16x8 afr = *(const bf16x8*)&Alds[(wm * 64 + mf * 16 + l15) * 40 + g * 8];
            for (int nf = 0; nf < 2; ++nf)
                acc[mf][nf] = __builtin_amdgcn_mfma_f32_16x16x32_bf16(afr, bfr[nf], acc[mf][nf], 0, 0, 0);
        }
        __syncthreads();
    }
    const float QSCALE = 0.0625f * 1.44269504088896f;   // (1/sqrt(256)) * log2(e)
    for (int mf = 0; mf < 4; ++mf) {
        for (int nf = 0; nf < 2; ++nf) {
            int o = O0 + wn * 32 + nf * 16 + l15;
            float bias = bqkv[o];
            for (int r = 0; r < 4; ++r) {
                int t = T0 + wm * 64 + mf * 16 + g * 4 + r;
                float val = acc[mf][nf][r] + bias;
                if (O0 < 256) {
                    q[((size_t)b * N + t) * C + o] = f2bf(val * QSCALE);
                } else if (O0 < 512) {
                    kt[((size_t)b * N + t) * C + (o - 256)] = f2bf(val);
                } else {
                    // permuted-token store for V (attn PV k-reorder)
                    int tp = (t & ~31) | ((g * 2 + (mf & 1)) * 4 + r);
                    v[((size_t)b * C + (o - 512)) * N + tp] = f2bf(val);
                }
            }
        }
    }
}

// ---------------- Kernel 3: flash attention (mrep=2, NSEG KV segments) --------
// Grid (N/128, NSEG, BB), 256 thr = 4 waves, 64KB LDS -> 2 blocks/CU (NSEG=4)
// with independent barriers (phase drift). Each wave owns 32 Q-rows as TWO
// 16-row fragment sets: every K/V ds_read feeds 2 MFMAs (halves LDS traffic).
// Swapped QK^T + zero-shuffle PV + defer-max as R9. Writes unnormalized
// O-partials (bf16) + m,l per segment; combine fused into out_gemm.
template<int NSEG>
__global__ __launch_bounds__(256, 2) void attn_k(
    const unsigned short* __restrict__ q, const unsigned short* __restrict__ kt,
    const unsigned short* __restrict__ v,
    unsigned short* __restrict__ P, float* __restrict__ ml)
{
    constexpr int NS  = N / NSEG;    // tokens per segment
    constexpr int NIT = NS / TS;     // tile iterations
    __shared__ unsigned short Klds[2][TS * 256];   // dbuf [tk][c-chunks^] 32KB
    __shared__ unsigned short Vlds[2][256 * TS];   // dbuf [c][tok-slots]  32KB

    int tid = threadIdx.x;
    int h  = blockIdx.y;          // KV segment
    int b  = blockIdx.z;
    int Q0 = blockIdx.x * 128;
    int lane = tid & 63;
    int lw = tid >> 6;            // wave = 32 Q rows
    int g = lane >> 4, l15 = lane & 15;

    // Q fragments (64 VGPR): two 16-row sets
    bf16x8 qf[2][8];
#pragma unroll
    for (int m = 0; m < 2; ++m) {
        const unsigned short* qp = q + ((size_t)b * N + Q0 + lw * 32 + m * 16 + l15) * C + g * 8;
#pragma unroll
        for (int kc = 0; kc < 8; ++kc)
            qf[m][kc] = *(const bf16x8*)(qp + kc * 32);
    }

    // O^T accumulators: oacc[m][cf][r] = O[q = m-set row l15][c = cf*16 + g*4 + r]
    f32x4 oacc[2][16];
#pragma unroll
    for (int m = 0; m < 2; ++m)
#pragma unroll
        for (int i = 0; i < 16; ++i) oacc[m][i] = f32x4{0.f, 0.f, 0.f, 0.f};
    float mrow[2] = {-1e30f, -1e30f}, lrow[2] = {0.f, 0.f};   // log2 domain

    const unsigned short* kb = kt + ((size_t)b * N + h * NS) * C;
    const unsigned short* vb = v + (size_t)b * C * N + h * NS;

#define STAGE(buf_, t_)                                                              \
    {                                                                                \
        const unsigned short* kbt = kb + (size_t)(t_) * TS * 256;                    \
        _Pragma("unroll")                                                            \
        for (int j = 0; j < 4; ++j) {                                                \
            int qq = tid + j * 256;                                                  \
            int tk = qq >> 5, sc = qq & 31;                                          \
            stage16(kbt + tk * 256 + ((sc ^ (tk & 7)) * 8), &Klds[buf_][qq * 8]);    \
        }                                                                            \
        _Pragma("unroll")                                                            \
        for (int j = 0; j < 4; ++j) {                                                \
            int qq = tid + j * 256;                                                  \
            int c = qq >> 2, sl = qq & 3;                                            \
            stage16(vb + (size_t)c * N + (t_) * TS + ((sl ^ ((c >> 1) & 3)) * 8),    \
                    &Vlds[buf_][qq * 8]);                                            \
        }                                                                            \
    }

    STAGE(0, 0);
    __syncthreads();   // drains vmcnt: tile 0 ready

    for (int t = 0; t < NIT; ++t) {
        int cur = t & 1;
        if (t < NIT - 1) STAGE(cur ^ 1, t + 1);   // issue next tile; hides under compute

        // S^T = K Q^T : kf read once, feeds both m-sets
        f32x4 st[2][2];
#pragma unroll
        for (int m = 0; m < 2; ++m)
#pragma unroll
            for (int ct = 0; ct < 2; ++ct) st[m][ct] = f32x4{0.f, 0.f, 0.f, 0.f};
        __builtin_amdgcn_s_setprio(1);
#pragma unroll
        for (int kc = 0; kc < 8; ++kc) {
#pragma unroll
            for (int ct = 0; ct < 2; ++ct) {
                int tk = ct * 16 + l15;
                int slot = (kc * 4 + g) ^ (tk & 7);
                bf16x8 kf = *(const bf16x8*)&Klds[cur][tk * 256 + slot * 8];
                st[0][ct] = __builtin_amdgcn_mfma_f32_16x16x32_bf16(kf, qf[0][kc], st[0][ct], 0, 0, 0);
                st[1][ct] = __builtin_amdgcn_mfma_f32_16x16x32_bf16(kf, qf[1][kc], st[1][ct], 0, 0, 0);
            }
        }
        __builtin_amdgcn_s_setprio(0);

        // per-lane online softmax with defer-max, per m-set
        float mx[2];
#pragma unroll
        for (int m = 0; m < 2; ++m) {
            float v0 = fmaxf(fmaxf(fmaxf(st[m][0][0], st[m][0][1]), fmaxf(st[m][0][2], st[m][0][3])),
                             fmaxf(fmaxf(st[m][1][0], st[m][1][1]), fmaxf(st[m][1][2], st[m][1][3])));
            v0 = fmaxf(v0, __shfl_xor(v0, 16));
            v0 = fmaxf(v0, __shfl_xor(v0, 32));
            mx[m] = v0;
        }
        bool ok = (mx[0] - mrow[0] <= 8.f) & (mx[1] - mrow[1] <= 8.f);
        if (!__all(ok)) {
#pragma unroll
            for (int m = 0; m < 2; ++m) {
                float mn = fmaxf(mrow[m], mx[m]);
                float alpha = exp2f(mrow[m] - mn);
                mrow[m] = mn;
                lrow[m] *= alpha;
#pragma unroll
                for (int f = 0; f < 16; ++f)
#pragma unroll
                    for (int r = 0; r < 4; ++r) oacc[m][f][r] *= alpha;
            }
        }
        bf16x8 pf[2];
#pragma unroll
        for (int m = 0; m < 2; ++m) {
            float rs = 0.f;
#pragma unroll
            for (int ct = 0; ct < 2; ++ct)
#pragma unroll
                for (int r = 0; r < 4; ++r) {
                    float p = exp2f(st[m][ct][r] - mrow[m]);
                    st[m][ct][r] = p;
                    rs += p;
                }
            rs += __shfl_xor(rs, 16);
            rs += __shfl_xor(rs, 32);
            lrow[m] += rs;
            u32x4 pk;
            pk[0] = cvt_pk_bf16(st[m][0][0], st[m][0][1]);
            pk[1] = cvt_pk_bf16(st[m][0][2], st[m][0][3]);
            pk[2] = cvt_pk_bf16(st[m][1][0], st[m][1][1]);
            pk[3] = cvt_pk_bf16(st[m][1][2], st[m][1][3]);
            pf[m] = __builtin_bit_cast(bf16x8, pk);
        }

        // O^T += V P (k-reordered, V pre-permuted): vf read once, feeds both m-sets
        __builtin_amdgcn_s_setprio(1);
#pragma unroll
        for (int cf = 0; cf < 16; ++cf) {
            int c = cf * 16 + l15;
            int vslot = g ^ ((c >> 1) & 3);
            bf16x8 vf = *(const bf16x8*)&Vlds[cur][c * TS + vslot * 8];
            oacc[0][cf] = __builtin_amdgcn_mfma_f32_16x16x32_bf16(vf, pf[0], oacc[0][cf], 0, 0, 0);
            oacc[1][cf] = __builtin_amdgcn_mfma_f32_16x16x32_bf16(vf, pf[1], oacc[1][cf], 0, 0, 0);
        }
        __builtin_amdgcn_s_setprio(0);
        __syncthreads();   // drains vmcnt: tile t+1 ready, buf cur free for t+2
    }

    // ---- epilogue: write unnormalized O-partials (bf16) + m,l per segment ----
#pragma unroll
    for (int m = 0; m < 2; ++m) {
        size_t tokid = (size_t)b * N + Q0 + lw * 32 + m * 16 + l15;
        if (g == 0) {
            ml[(size_t)(2 * h + 0) * (BB * N) + tokid] = mrow[m];
            ml[(size_t)(2 * h + 1) * (BB * N) + tokid] = lrow[m];
        }
        unsigned short* pp = P + (size_t)h * BB * N * C + tokid * C;
#pragma unroll
        for (int cf = 0; cf < 16; ++cf) {
#pragma unroll
            for (int rp = 0; rp < 2; ++rp) {
                int c = cf * 16 + g * 4 + rp * 2;
                unsigned int pk2 = cvt_pk_bf16(oacc[m][cf][rp * 2 + 0], oacc[m][cf][rp * 2 + 1]);
                *(unsigned int*)&pp[c] = pk2;
            }
        }
    }
}

// ---------------- Kernel 4: out projection + bias + residual (+fused combine) --
// B-staging reads the NSEG unnormalized partials + m,l and combines on the fly.
template<int NSEG>
__global__ __launch_bounds__(256) void out_gemm_k(
    const unsigned short* __restrict__ P, const float* __restrict__ ml,
    const float* __restrict__ Wout, const float* __restrict__ bout,
    const float* __restrict__ x, float* __restrict__ out)
{
    __shared__ unsigned short Alds[64 * 72];
    __shared__ unsigned short Blds[128 * 72];
    int tid = threadIdx.x;
    int b   = blockIdx.z;
    int CO0 = blockIdx.y * 64;
    int T0  = blockIdx.x * 128;
    int lane = tid & 63;
    int w = tid >> 6;
    int wm = w >> 1, wn = w & 1;
    int g = lane >> 4, l15 = lane & 15;

    f32x4 acc[2][4];
    for (int i = 0; i < 2; ++i)
        for (int j = 0; j < 4; ++j) acc[i][j] = f32x4{0.f, 0.f, 0.f, 0.f};

    int a_r = tid >> 2;
    int a_cb = (tid & 3) * 16;

    // combine weights for this thread's 4 staged tokens (tl = (tid + it*256)>>3)
    float cw[4][NSEG];
    float cinv[4];
#pragma unroll
    for (int it = 0; it < 4; ++it) {
        int tl = (tid + it * 256) >> 3;
        size_t tok = (size_t)b * N + T0 + tl;
        float ms[NSEG], ls[NSEG];
#pragma unroll
        for (int s = 0; s < NSEG; ++s) {
            ms[s] = ml[(size_t)(2 * s + 0) * (BB * N) + tok];
            ls[s] = ml[(size_t)(2 * s + 1) * (BB * N) + tok];
        }
        float M = ms[0];
#pragma unroll
        for (int s = 1; s < NSEG; ++s) M = fmaxf(M, ms[s]);
        float den = 0.f;
#pragma unroll
        for (int s = 0; s < NSEG; ++s) {
            cw[it][s] = exp2f(ms[s] - M);
            den += cw[it][s] * ls[s];
        }
        cinv[it] = 1.f / den;
    }

    for (int c0 = 0; c0 < C; c0 += 64) {
        {
            const float4* wp = (const float4*)(Wout + (size_t)(CO0 + a_r) * C + c0 + a_cb);
            for (int j = 0; j < 4; ++j) {
                float4 vv = wp[j];
                int base = a_r * 72 + a_cb + j * 4;
                Alds[base + 0] = f2bf(vv.x);
                Alds[base + 1] = f2bf(vv.y);
                Alds[base + 2] = f2bf(vv.z);
                Alds[base + 3] = f2bf(vv.w);
            }
        }
#pragma unroll
        for (int it = 0; it < 4; ++it) {
            int chunk = tid + it * 256;
            int tl = chunk >> 3, j = chunk & 7;
            size_t base = ((size_t)b * N + T0 + tl) * C + c0 + j * 8;
            float val[8];
#pragma unroll
            for (int e = 0; e < 8; ++e) val[e] = 0.f;
#pragma unroll
            for (int s = 0; s < NSEG; ++s) {
                bf16x8 p = *(const bf16x8*)(P + (size_t)s * BB * N * C + base);
                float wgt = cw[it][s];
#pragma unroll
                for (int e = 0; e < 8; ++e) val[e] += wgt * bf2f((unsigned short)p[e]);
            }
            unsigned int opk[4];
#pragma unroll
            for (int jj = 0; jj < 4; ++jj)
                opk[jj] = cvt_pk_bf16(val[2 * jj] * cinv[it], val[2 * jj + 1] * cinv[it]);
            *(u32x4*)&Blds[tl * 72 + j * 8] = *(u32x4*)opk;
        }
        __syncthreads();
        for (int kk = 0; kk < 2; ++kk) {
            bf16x8 bfr[4];
            for (int nf = 0; nf < 4; ++nf)
                bfr[nf] = *(const bf16x8*)&Blds[(wn * 64 + nf * 16 + l15) * 72 + kk * 32 + g * 8];
            for (int mf = 0; mf < 2; ++mf) {
                bf16x8 afr = *(const bf16x8*)&Alds[(wm * 32 + mf * 16 + l15) * 72 + kk * 32 + g * 8];
                for (int nf = 0; nf < 4; ++nf)
                    acc[mf][nf] = __builtin_amdgcn_mfma_f32_16x16x32_bf16(afr, bfr[nf], acc[mf][nf], 0, 0, 0);
            }
        }
        __syncthreads();
    }
    for (int mf = 0; mf < 2; ++mf) {
        for (int nf = 0; nf < 4; ++nf) {
            int t = T0 + wn * 64 + nf * 16 + l15;
            for (int r = 0; r < 4; ++r) {
                int co = CO0 + wm * 32 + mf * 16 + g * 4 + r;
                size_t oidx = ((size_t)b * C + co) * N + t;
                out[oidx] = acc[mf][nf][r] + bout[co] + x[oidx];
            }
        }
    }
}

extern "C" void kernel_launch(void* const* d_in, const int* in_sizes, int n_in,
                              void* d_out, int out_size, void* d_ws, size_t ws_size,
                              hipStream_t stream) {
    const float* x     = (const float*)d_in[0];
    const float* Wqkv  = (const float*)d_in[1];
    const float* bqkv  = (const float*)d_in[2];
    const float* Wout  = (const float*)d_in[3];
    const float* bout  = (const float*)d_in[4];
    const float* gamma = (const float*)d_in[5];
    const float* beta  = (const float*)d_in[6];
    float* out = (float*)d_out;

    const size_t BBNC = (size_t)BB * N * C;          // elements
    char* ws = (char*)d_ws;
    float* scale = (float*)ws;
    float* shift = (float*)(ws + 1024);
    unsigned short* q  = (unsigned short*)(ws + 4096);
    unsigned short* kt = q  + BBNC;
    unsigned short* v  = kt + BBNC;
    unsigned short* P  = v  + BBNC;

    // ws requirement: 4096 + (3 + NSEG)*BBNC*2 + 2*NSEG*BB*N*4 bytes
    size_t need4 = 4096 + 7 * BBNC * 2 + (size_t)8 * BB * N * 4;

    bn_stats_k<<<dim3(C), dim3(256), 0, stream>>>(x, gamma, beta, scale, shift);
    qkv_gemm_k<<<dim3(12, 32, BB), dim3(256), 0, stream>>>(x, Wqkv, bqkv, scale, shift, q, kt, v);

    if (ws_size >= need4) {
        float* ml = (float*)(P + 4 * BBNC);
        attn_k<4><<<dim3(N / 128, 4, BB), dim3(256), 0, stream>>>(q, kt, v, P, ml);
        out_gemm_k<4><<<dim3(32, 4, BB), dim3(256), 0, stream>>>(P, ml, Wout, bout, x, out);
    } else {
        float* ml = (float*)(P + 2 * BBNC);
        attn_k<2><<<dim3(N / 128, 2, BB), dim3(256), 0, stream>>>(q, kt, v, P, ml);
        out_gemm_k<2><<<dim3(32, 4, BB), dim3(256), 0, stream>>>(P, ml, Wout, bout, x, out);
    }
}

// Round 11
// 152.539 us; speedup vs baseline: 2.1302x; 1.1214x over previous
//
#include <hip/hip_runtime.h>
#include <hip/hip_bf16.h>

typedef __attribute__((ext_vector_type(4))) float f32x4;
typedef __attribute__((ext_vector_type(8))) short bf16x8;
typedef __attribute__((ext_vector_type(4))) unsigned int u32x4;

#define BB 4
#define C 256
#define N 4096
#define TS 32
#define EPSI 1e-5f

constexpr size_t BBNC = (size_t)BB * N * C;

__device__ __forceinline__ unsigned short f2bf(float f) {
    unsigned int u = __builtin_bit_cast(unsigned int, f);
    u += 0x7fffu + ((u >> 16) & 1u);
    return (unsigned short)(u >> 16);
}

__device__ __forceinline__ float bf2f(unsigned short h) {
    unsigned int u = ((unsigned int)h) << 16;
    return __builtin_bit_cast(float, u);
}

__device__ __forceinline__ unsigned int cvt_pk_bf16(float lo, float hi) {
    unsigned int r;
    asm("v_cvt_pk_bf16_f32 %0, %1, %2" : "=v"(r) : "v"(lo), "v"(hi));
    return r;
}

// async global->LDS, 16B per lane; LDS dest is uniform-base + linear per-lane offset.
__device__ __forceinline__ void stage16(const unsigned short* g, unsigned short* l) {
    __builtin_amdgcn_global_load_lds(
        (const __attribute__((address_space(1))) void*)g,
        (__attribute__((address_space(3))) void*)l, 16, 0, 0);
}

// ---------------- Kernel 0: Wqkv fp32 -> bf16 (into P-alias region) ----------------
__global__ __launch_bounds__(256) void w2bf_k(const float* __restrict__ W,
                                              unsigned short* __restrict__ wb)
{
    size_t i = (size_t)blockIdx.x * 256 + threadIdx.x;   // chunk of 8 elems
    const float4* p = (const float4*)(W + i * 8);
    float4 a = p[0], c = p[1];
    unsigned int pk[4];
    pk[0] = cvt_pk_bf16(a.x, a.y);
    pk[1] = cvt_pk_bf16(a.z, a.w);
    pk[2] = cvt_pk_bf16(c.x, c.y);
    pk[3] = cvt_pk_bf16(c.z, c.w);
    *(u32x4*)(wb + i * 8) = *(u32x4*)pk;
}

// ---------------- Kernel 1: BN stats -> scale/shift per channel ----------------
__global__ __launch_bounds__(256) void bn_stats_k(
    const float* __restrict__ x, const float* __restrict__ gamma,
    const float* __restrict__ beta, float* __restrict__ scale, float* __restrict__ shift)
{
    int c = blockIdx.x;
    int tid = threadIdx.x;
    float s = 0.f, s2 = 0.f;
    for (int b = 0; b < BB; ++b) {
        const float4* p = (const float4*)(x + ((size_t)b * C + c) * N);
        for (int i = tid; i < N / 4; i += 256) {
            float4 v = p[i];
            s  += v.x + v.y + v.z + v.w;
            s2 += v.x * v.x + v.y * v.y + v.z * v.z + v.w * v.w;
        }
    }
    for (int m = 1; m < 64; m <<= 1) {
        s  += __shfl_xor(s, m);
        s2 += __shfl_xor(s2, m);
    }
    __shared__ float rs[4], rs2[4];
    int w = tid >> 6;
    if ((tid & 63) == 0) { rs[w] = s; rs2[w] = s2; }
    __syncthreads();
    if (tid == 0) {
        float S  = rs[0] + rs[1] + rs[2] + rs[3];
        float S2 = rs2[0] + rs2[1] + rs2[2] + rs2[3];
        const float inv_n = 1.f / (BB * N);
        float mean = S * inv_n;
        float var  = S2 * inv_n - mean * mean;
        float sc = gamma[c] * rsqrtf(var + EPSI);
        scale[c] = sc;
        shift[c] = beta[c] - mean * sc;
    }
}

// ---------------- Kernel 2: fused BN-apply + QKV projection (x read ONCE) ------
// Grid (N/32, BB) = 512 blocks (2/CU). A-tile (32 t x 256 c, BN'd, transposed)
// staged once in LDS [32][264] (33 slots/row, conflict-free frag reads). Then 12
// O-iters: W-tile (64 o x 256 c bf16) staged via global_load_lds + XOR swizzle
// (attn-K pattern). Softmax scale (1/16*log2e) folded into q; V token-permuted.
__global__ __launch_bounds__(256) void qkv_gemm_k(
    const float* __restrict__ x, const unsigned short* __restrict__ wqkv_bf,
    const float* __restrict__ bqkv,
    const float* __restrict__ scale, const float* __restrict__ shift,
    unsigned short* __restrict__ q, unsigned short* __restrict__ kt, unsigned short* __restrict__ v)
{
    __shared__ unsigned short Alds[32 * 264];   // [t][c], stride 264
    __shared__ unsigned short Wlds[64 * 256];   // [o][c-chunks^], gload_lds + XOR

    int tid = threadIdx.x;
    int b  = blockIdx.y;
    int T0 = blockIdx.x * 32;
    int lane = tid & 63;
    int w = tid >> 6;
    int wm = w >> 1, wn = w & 1;
    int g = lane >> 4, l15 = lane & 15;

    // stage A once: transpose + BN + bf16
    {
        int cbase = tid >> 1;          // 0..127
        int t0 = (tid & 1) * 16;
#pragma unroll
        for (int pass = 0; pass < 2; ++pass) {
            int cc = cbase + pass * 128;
            const float4* xp = (const float4*)(x + ((size_t)b * C + cc) * N + T0 + t0);
            float sc = scale[cc], sh = shift[cc];
#pragma unroll
            for (int j = 0; j < 4; ++j) {
                float4 vv = xp[j];
                int t = t0 + j * 4;
                Alds[(t + 0) * 264 + cc] = f2bf(vv.x * sc + sh);
                Alds[(t + 1) * 264 + cc] = f2bf(vv.y * sc + sh);
                Alds[(t + 2) * 264 + cc] = f2bf(vv.z * sc + sh);
                Alds[(t + 3) * 264 + cc] = f2bf(vv.w * sc + sh);
            }
        }
    }

    const float QSCALE = 0.0625f * 1.44269504088896f;   // (1/sqrt(256)) * log2(e)

    for (int oi = 0; oi < 12; ++oi) {
        int O0 = oi * 64;
        __syncthreads();   // protect Wlds (and, at oi=0, publish Alds)
        {   // stage W tile via gload_lds, XOR'd global source (rule 21)
            const unsigned short* wb = wqkv_bf + (size_t)O0 * 256;
#pragma unroll
            for (int j = 0; j < 8; ++j) {
                int qq = tid + j * 256;
                int lo = qq >> 5, sc2 = qq & 31;
                stage16(wb + (size_t)lo * 256 + ((sc2 ^ (lo & 7)) * 8), &Wlds[qq * 8]);
            }
        }
        __syncthreads();   // drains vmcnt: W tile ready

        f32x4 acc[2];
        acc[0] = f32x4{0.f, 0.f, 0.f, 0.f};
        acc[1] = f32x4{0.f, 0.f, 0.f, 0.f};
#pragma unroll
        for (int kk = 0; kk < 8; ++kk) {
            bf16x8 afr = *(const bf16x8*)&Alds[(wm * 16 + l15) * 264 + kk * 32 + g * 8];
#pragma unroll
            for (int nf = 0; nf < 2; ++nf) {
                int lo = wn * 32 + nf * 16 + l15;
                bf16x8 bfr = *(const bf16x8*)&Wlds[lo * 256 + (((kk * 4 + g) ^ (lo & 7)) * 8)];
                acc[nf] = __builtin_amdgcn_mfma_f32_16x16x32_bf16(afr, bfr, acc[nf], 0, 0, 0);
            }
        }

        // epilogue for this O-tile
#pragma unroll
        for (int nf = 0; nf < 2; ++nf) {
            int o = O0 + wn * 32 + nf * 16 + l15;
            float bias = bqkv[o];
#pragma unroll
            for (int r = 0; r < 4; ++r) {
                int t = T0 + wm * 16 + g * 4 + r;
                float val = acc[nf][r] + bias;
                if (O0 < 256) {
                    q[((size_t)b * N + t) * C + o] = f2bf(val * QSCALE);
                } else if (O0 < 512) {
                    kt[((size_t)b * N + t) * C + (o - 256)] = f2bf(val);
                } else {
                    // permuted-token store for V (attn PV k-reorder); wm = t-bit4
                    int tp = (t & ~31) | ((g * 2 + wm) * 4 + r);
                    v[((size_t)b * C + (o - 512)) * N + tp] = f2bf(val);
                }
            }
        }
    }
}

// ---------------- Kernel 3: flash attention (mrep=2, NSEG KV segments) --------
// UNCHANGED from R10 (proven: 102 us, no spill).
template<int NSEG>
__global__ __launch_bounds__(256, 2) void attn_k(
    const unsigned short* __restrict__ q, const unsigned short* __restrict__ kt,
    const unsigned short* __restrict__ v,
    unsigned short* __restrict__ P, float* __restrict__ ml)
{
    constexpr int NS  = N / NSEG;    // tokens per segment
    constexpr int NIT = NS / TS;     // tile iterations
    __shared__ unsigned short Klds[2][TS * 256];   // dbuf [tk][c-chunks^] 32KB
    __shared__ unsigned short Vlds[2][256 * TS];   // dbuf [c][tok-slots]  32KB

    int tid = threadIdx.x;
    int h  = blockIdx.y;          // KV segment
    int b  = blockIdx.z;
    int Q0 = blockIdx.x * 128;
    int lane = tid & 63;
    int lw = tid >> 6;            // wave = 32 Q rows
    int g = lane >> 4, l15 = lane & 15;

    bf16x8 qf[2][8];
#pragma unroll
    for (int m = 0; m < 2; ++m) {
        const unsigned short* qp = q + ((size_t)b * N + Q0 + lw * 32 + m * 16 + l15) * C + g * 8;
#pragma unroll
        for (int kc = 0; kc < 8; ++kc)
            qf[m][kc] = *(const bf16x8*)(qp + kc * 32);
    }

    f32x4 oacc[2][16];
#pragma unroll
    for (int m = 0; m < 2; ++m)
#pragma unroll
        for (int i = 0; i < 16; ++i) oacc[m][i] = f32x4{0.f, 0.f, 0.f, 0.f};
    float mrow[2] = {-1e30f, -1e30f}, lrow[2] = {0.f, 0.f};   // log2 domain

    const unsigned short* kb = kt + ((size_t)b * N + h * NS) * C;
    const unsigned short* vb = v + (size_t)b * C * N + h * NS;

#define STAGE(buf_, t_)                                                              \
    {                                                                                \
        const unsigned short* kbt = kb + (size_t)(t_) * TS * 256;                    \
        _Pragma("unroll")                                                            \
        for (int j = 0; j < 4; ++j) {                                                \
            int qq = tid + j * 256;                                                  \
            int tk = qq >> 5, sc = qq & 31;                                          \
            stage16(kbt + tk * 256 + ((sc ^ (tk & 7)) * 8), &Klds[buf_][qq * 8]);    \
        }                                                                            \
        _Pragma("unroll")                                                            \
        for (int j = 0; j < 4; ++j) {                                                \
            int qq = tid + j * 256;                                                  \
            int c = qq >> 2, sl = qq & 3;                                            \
            stage16(vb + (size_t)c * N + (t_) * TS + ((sl ^ ((c >> 1) & 3)) * 8),    \
                    &Vlds[buf_][qq * 8]);                                            \
        }                                                                            \
    }

    STAGE(0, 0);
    __syncthreads();

    for (int t = 0; t < NIT; ++t) {
        int cur = t & 1;
        if (t < NIT - 1) STAGE(cur ^ 1, t + 1);

        f32x4 st[2][2];
#pragma unroll
        for (int m = 0; m < 2; ++m)
#pragma unroll
            for (int ct = 0; ct < 2; ++ct) st[m][ct] = f32x4{0.f, 0.f, 0.f, 0.f};
        __builtin_amdgcn_s_setprio(1);
#pragma unroll
        for (int kc = 0; kc < 8; ++kc) {
#pragma unroll
            for (int ct = 0; ct < 2; ++ct) {
                int tk = ct * 16 + l15;
                int slot = (kc * 4 + g) ^ (tk & 7);
                bf16x8 kf = *(const bf16x8*)&Klds[cur][tk * 256 + slot * 8];
                st[0][ct] = __builtin_amdgcn_mfma_f32_16x16x32_bf16(kf, qf[0][kc], st[0][ct], 0, 0, 0);
                st[1][ct] = __builtin_amdgcn_mfma_f32_16x16x32_bf16(kf, qf[1][kc], st[1][ct], 0, 0, 0);
            }
        }
        __builtin_amdgcn_s_setprio(0);

        float mx[2];
#pragma unroll
        for (int m = 0; m < 2; ++m) {
            float v0 = fmaxf(fmaxf(fmaxf(st[m][0][0], st[m][0][1]), fmaxf(st[m][0][2], st[m][0][3])),
                             fmaxf(fmaxf(st[m][1][0], st[m][1][1]), fmaxf(st[m][1][2], st[m][1][3])));
            v0 = fmaxf(v0, __shfl_xor(v0, 16));
            v0 = fmaxf(v0, __shfl_xor(v0, 32));
            mx[m] = v0;
        }
        bool ok = (mx[0] - mrow[0] <= 8.f) & (mx[1] - mrow[1] <= 8.f);
        if (!__all(ok)) {
#pragma unroll
            for (int m = 0; m < 2; ++m) {
                float mn = fmaxf(mrow[m], mx[m]);
                float alpha = exp2f(mrow[m] - mn);
                mrow[m] = mn;
                lrow[m] *= alpha;
#pragma unroll
                for (int f = 0; f < 16; ++f)
#pragma unroll
                    for (int r = 0; r < 4; ++r) oacc[m][f][r] *= alpha;
            }
        }
        bf16x8 pf[2];
#pragma unroll
        for (int m = 0; m < 2; ++m) {
            float rs = 0.f;
#pragma unroll
            for (int ct = 0; ct < 2; ++ct)
#pragma unroll
                for (int r = 0; r < 4; ++r) {
                    float p = exp2f(st[m][ct][r] - mrow[m]);
                    st[m][ct][r] = p;
                    rs += p;
                }
            rs += __shfl_xor(rs, 16);
            rs += __shfl_xor(rs, 32);
            lrow[m] += rs;
            u32x4 pk;
            pk[0] = cvt_pk_bf16(st[m][0][0], st[m][0][1]);
            pk[1] = cvt_pk_bf16(st[m][0][2], st[m][0][3]);
            pk[2] = cvt_pk_bf16(st[m][1][0], st[m][1][1]);
            pk[3] = cvt_pk_bf16(st[m][1][2], st[m][1][3]);
            pf[m] = __builtin_bit_cast(bf16x8, pk);
        }

        __builtin_amdgcn_s_setprio(1);
#pragma unroll
        for (int cf = 0; cf < 16; ++cf) {
            int c = cf * 16 + l15;
            int vslot = g ^ ((c >> 1) & 3);
            bf16x8 vf = *(const bf16x8*)&Vlds[cur][c * TS + vslot * 8];
            oacc[0][cf] = __builtin_amdgcn_mfma_f32_16x16x32_bf16(vf, pf[0], oacc[0][cf], 0, 0, 0);
            oacc[1][cf] = __builtin_amdgcn_mfma_f32_16x16x32_bf16(vf, pf[1], oacc[1][cf], 0, 0, 0);
        }
        __builtin_amdgcn_s_setprio(0);
        __syncthreads();
    }

#pragma unroll
    for (int m = 0; m < 2; ++m) {
        size_t tokid = (size_t)b * N + Q0 + lw * 32 + m * 16 + l15;
        if (g == 0) {
            ml[(size_t)(2 * h + 0) * (BB * N) + tokid] = mrow[m];
            ml[(size_t)(2 * h + 1) * (BB * N) + tokid] = lrow[m];
        }
        unsigned short* pp = P + (size_t)h * BBNC + tokid * C;
#pragma unroll
        for (int cf = 0; cf < 16; ++cf) {
#pragma unroll
            for (int rp = 0; rp < 2; ++rp) {
                int c = cf * 16 + g * 4 + rp * 2;
                unsigned int pk2 = cvt_pk_bf16(oacc[m][cf][rp * 2 + 0], oacc[m][cf][rp * 2 + 1]);
                *(unsigned int*)&pp[c] = pk2;
            }
        }
    }
}

// ---------------- Kernel 4: out projection + combine (P read ONCE) ------------
// Grid (N/32, BB) = 512 blocks (2/CU). Each block: 32 tokens x ALL 256 out
// channels. B-staging combines the NSEG partials on the fly (once per element).
template<int NSEG>
__global__ __launch_bounds__(256) void out_gemm_k(
    const unsigned short* __restrict__ P, const float* __restrict__ ml,
    const float* __restrict__ Wout, const float* __restrict__ bout,
    const float* __restrict__ x, float* __restrict__ out)
{
    __shared__ unsigned short Alds[256 * 40];   // Wout [co][32c] bf16, pad 40
    __shared__ unsigned short Blds[32 * 40];    // combined ao [t][32c]

    int tid = threadIdx.x;
    int b  = blockIdx.y;
    int T0 = blockIdx.x * 32;
    int lane = tid & 63;
    int w = tid >> 6;
    int g = lane >> 4, l15 = lane & 15;

    // combine weights for this thread's staged token (threads 0..127 stage B)
    int tl = (tid >> 2) & 31;
    float cw[NSEG], cinv;
    {
        size_t tok = (size_t)b * N + T0 + tl;
        float ms[NSEG], ls[NSEG];
#pragma unroll
        for (int s = 0; s < NSEG; ++s) {
            ms[s] = ml[(size_t)(2 * s + 0) * (BB * N) + tok];
            ls[s] = ml[(size_t)(2 * s + 1) * (BB * N) + tok];
        }
        float M = ms[0];
#pragma unroll
        for (int s = 1; s < NSEG; ++s) M = fmaxf(M, ms[s]);
        float den = 0.f;
#pragma unroll
        for (int s = 0; s < NSEG; ++s) {
            cw[s] = exp2f(ms[s] - M);
            den += cw[s] * ls[s];
        }
        cinv = 1.f / den;
    }

    f32x4 acc[4][2];
#pragma unroll
    for (int i = 0; i < 4; ++i)
#pragma unroll
        for (int j = 0; j < 2; ++j) acc[i][j] = f32x4{0.f, 0.f, 0.f, 0.f};

    for (int c0 = 0; c0 < C; c0 += 32) {
        if (c0) __syncthreads();   // protect LDS from previous iter's readers
        {   // stage A: Wout[tid][c0..c0+32) fp32 -> bf16
            const float4* wp = (const float4*)(Wout + (size_t)tid * C + c0);
            unsigned int wpk[16];
#pragma unroll
            for (int j = 0; j < 8; ++j) {
                float4 vv = wp[j];
                wpk[2 * j + 0] = cvt_pk_bf16(vv.x, vv.y);
                wpk[2 * j + 1] = cvt_pk_bf16(vv.z, vv.w);
            }
#pragma unroll
            for (int j = 0; j < 16; ++j)
                *(unsigned int*)&Alds[tid * 40 + j * 2] = wpk[j];
        }
        if (tid < 128) {   // stage B: combine NSEG partials
            int j = tid & 3;
            size_t base = ((size_t)b * N + T0 + tl) * C + c0 + j * 8;
            float val[8];
#pragma unroll
            for (int e = 0; e < 8; ++e) val[e] = 0.f;
#pragma unroll
            for (int s = 0; s < NSEG; ++s) {
                bf16x8 p = *(const bf16x8*)(P + (size_t)s * BBNC + base);
                float wgt = cw[s];
#pragma unroll
                for (int e = 0; e < 8; ++e) val[e] += wgt * bf2f((unsigned short)p[e]);
            }
            unsigned int opk[4];
#pragma unroll
            for (int jj = 0; jj < 4; ++jj)
                opk[jj] = cvt_pk_bf16(val[2 * jj] * cinv, val[2 * jj + 1] * cinv);
            *(u32x4*)&Blds[tl * 40 + j * 8] = *(u32x4*)opk;
        }
        __syncthreads();

        bf16x8 afr[4];
#pragma unroll
        for (int mf = 0; mf < 4; ++mf)
            afr[mf] = *(const bf16x8*)&Alds[(w * 64 + mf * 16 + l15) * 40 + g * 8];
#pragma unroll
        for (int tf = 0; tf < 2; ++tf) {
            bf16x8 bfr = *(const bf16x8*)&Blds[(tf * 16 + l15) * 40 + g * 8];
#pragma unroll
            for (int mf = 0; mf < 4; ++mf)
                acc[mf][tf] = __builtin_amdgcn_mfma_f32_16x16x32_bf16(afr[mf], bfr, acc[mf][tf], 0, 0, 0);
        }
    }

    // epilogue: out[b][co][t] = acc + bias + residual
#pragma unroll
    for (int mf = 0; mf < 4; ++mf) {
#pragma unroll
        for (int tf = 0; tf < 2; ++tf) {
            int t = T0 + tf * 16 + l15;
#pragma unroll
            for (int r = 0; r < 4; ++r) {
                int co = w * 64 + mf * 16 + g * 4 + r;
                size_t oidx = ((size_t)b * C + co) * N + t;
                out[oidx] = acc[mf][tf][r] + bout[co] + x[oidx];
            }
        }
    }
}

extern "C" void kernel_launch(void* const* d_in, const int* in_sizes, int n_in,
                              void* d_out, int out_size, void* d_ws, size_t ws_size,
                              hipStream_t stream) {
    const float* x     = (const float*)d_in[0];
    const float* Wqkv  = (const float*)d_in[1];
    const float* bqkv  = (const float*)d_in[2];
    const float* Wout  = (const float*)d_in[3];
    const float* bout  = (const float*)d_in[4];
    const float* gamma = (const float*)d_in[5];
    const float* beta  = (const float*)d_in[6];
    float* out = (float*)d_out;

    char* ws = (char*)d_ws;
    float* scale = (float*)ws;
    float* shift = (float*)(ws + 1024);
    unsigned short* q  = (unsigned short*)(ws + 4096);
    unsigned short* kt = q  + BBNC;
    unsigned short* v  = kt + BBNC;
    unsigned short* P  = v  + BBNC;
    // Wqkv-bf16 aliases P: written first, consumed by qkv_gemm, then attn overwrites P.
    unsigned short* wqkv_bf = P;

    size_t need4 = 4096 + 7 * BBNC * 2 + (size_t)8 * BB * N * 4;

    w2bf_k<<<dim3(768 * 256 / 8 / 256), dim3(256), 0, stream>>>(Wqkv, wqkv_bf);
    bn_stats_k<<<dim3(C), dim3(256), 0, stream>>>(x, gamma, beta, scale, shift);
    qkv_gemm_k<<<dim3(N / 32, BB), dim3(256), 0, stream>>>(x, wqkv_bf, bqkv, scale, shift, q, kt, v);

    if (ws_size >= need4) {
        float* ml = (float*)(P + 4 * BBNC);
        attn_k<4><<<dim3(N / 128, 4, BB), dim3(256), 0, stream>>>(q, kt, v, P, ml);
        out_gemm_k<4><<<dim3(N / 32, BB), dim3(256), 0, stream>>>(P, ml, Wout, bout, x, out);
    } else {
        float* ml = (float*)(P + 2 * BBNC);
        attn_k<2><<<dim3(N / 128, 2, BB), dim3(256), 0, stream>>>(q, kt, v, P, ml);
        out_gemm_k<2><<<dim3(N / 32, BB), dim3(256), 0, stream>>>(P, ml, Wout, bout, x, out);
    }
}

// Round 12
// 149.354 us; speedup vs baseline: 2.1756x; 1.0213x over previous
//
#include <hip/hip_runtime.h>
#include <hip/hip_bf16.h>

typedef __attribute__((ext_vector_type(4))) float f32x4;
typedef __attribute__((ext_vector_type(8))) short bf16x8;
typedef __attribute__((ext_vector_type(4))) unsigned int u32x4;

#define BB 4
#define C 256
#define N 4096
#define TS 32
#define EPSI 1e-5f

constexpr size_t BBNC = (size_t)BB * N * C;

__device__ __forceinline__ unsigned short f2bf(float f) {
    unsigned int u = __builtin_bit_cast(unsigned int, f);
    u += 0x7fffu + ((u >> 16) & 1u);
    return (unsigned short)(u >> 16);
}

__device__ __forceinline__ float bf2f(unsigned short h) {
    unsigned int u = ((unsigned int)h) << 16;
    return __builtin_bit_cast(float, u);
}

__device__ __forceinline__ unsigned int cvt_pk_bf16(float lo, float hi) {
    unsigned int r;
    asm("v_cvt_pk_bf16_f32 %0, %1, %2" : "=v"(r) : "v"(lo), "v"(hi));
    return r;
}

// async global->LDS, 16B per lane; LDS dest is uniform-base + linear per-lane offset.
__device__ __forceinline__ void stage16(const unsigned short* g, unsigned short* l) {
    __builtin_amdgcn_global_load_lds(
        (const __attribute__((address_space(1))) void*)g,
        (__attribute__((address_space(3))) void*)l, 16, 0, 0);
}

// ---------------- Kernel 1: BN stats + (fused) Wqkv fp32->bf16 ----------------
// Blocks [0,C): per-channel BN stats. Blocks [C, C+96): convert Wqkv to bf16.
__global__ __launch_bounds__(256) void bn_stats_k(
    const float* __restrict__ x, const float* __restrict__ gamma,
    const float* __restrict__ beta, float* __restrict__ scale, float* __restrict__ shift,
    const float* __restrict__ Wqkv, unsigned short* __restrict__ wqkv_bf)
{
    int tid = threadIdx.x;
    if (blockIdx.x >= C) {
        size_t i = ((size_t)(blockIdx.x - C) * 256 + tid);   // chunk of 8 elems
        const float4* p = (const float4*)(Wqkv + i * 8);
        float4 a = p[0], c = p[1];
        unsigned int pk[4];
        pk[0] = cvt_pk_bf16(a.x, a.y);
        pk[1] = cvt_pk_bf16(a.z, a.w);
        pk[2] = cvt_pk_bf16(c.x, c.y);
        pk[3] = cvt_pk_bf16(c.z, c.w);
        *(u32x4*)(wqkv_bf + i * 8) = *(u32x4*)pk;
        return;
    }
    int c = blockIdx.x;
    float s = 0.f, s2 = 0.f;
    for (int b = 0; b < BB; ++b) {
        const float4* p = (const float4*)(x + ((size_t)b * C + c) * N);
        for (int i = tid; i < N / 4; i += 256) {
            float4 v = p[i];
            s  += v.x + v.y + v.z + v.w;
            s2 += v.x * v.x + v.y * v.y + v.z * v.z + v.w * v.w;
        }
    }
    for (int m = 1; m < 64; m <<= 1) {
        s  += __shfl_xor(s, m);
        s2 += __shfl_xor(s2, m);
    }
    __shared__ float rs[4], rs2[4];
    int w = tid >> 6;
    if ((tid & 63) == 0) { rs[w] = s; rs2[w] = s2; }
    __syncthreads();
    if (tid == 0) {
        float S  = rs[0] + rs[1] + rs[2] + rs[3];
        float S2 = rs2[0] + rs2[1] + rs2[2] + rs2[3];
        const float inv_n = 1.f / (BB * N);
        float mean = S * inv_n;
        float var  = S2 * inv_n - mean * mean;
        float sc = gamma[c] * rsqrtf(var + EPSI);
        scale[c] = sc;
        shift[c] = beta[c] - mean * sc;
    }
}

// ---------------- Kernel 2: fused BN-apply + QKV projection (x read ONCE) ------
__global__ __launch_bounds__(256) void qkv_gemm_k(
    const float* __restrict__ x, const unsigned short* __restrict__ wqkv_bf,
    const float* __restrict__ bqkv,
    const float* __restrict__ scale, const float* __restrict__ shift,
    unsigned short* __restrict__ q, unsigned short* __restrict__ kt, unsigned short* __restrict__ v)
{
    __shared__ unsigned short Alds[32 * 264];   // [t][c], stride 264
    __shared__ unsigned short Wlds[64 * 256];   // [o][c-chunks^], gload_lds + XOR

    int tid = threadIdx.x;
    int b  = blockIdx.y;
    int T0 = blockIdx.x * 32;
    int lane = tid & 63;
    int w = tid >> 6;
    int wm = w >> 1, wn = w & 1;
    int g = lane >> 4, l15 = lane & 15;

    // stage A once: transpose + BN + bf16
    {
        int cbase = tid >> 1;          // 0..127
        int t0 = (tid & 1) * 16;
#pragma unroll
        for (int pass = 0; pass < 2; ++pass) {
            int cc = cbase + pass * 128;
            const float4* xp = (const float4*)(x + ((size_t)b * C + cc) * N + T0 + t0);
            float sc = scale[cc], sh = shift[cc];
#pragma unroll
            for (int j = 0; j < 4; ++j) {
                float4 vv = xp[j];
                int t = t0 + j * 4;
                Alds[(t + 0) * 264 + cc] = f2bf(vv.x * sc + sh);
                Alds[(t + 1) * 264 + cc] = f2bf(vv.y * sc + sh);
                Alds[(t + 2) * 264 + cc] = f2bf(vv.z * sc + sh);
                Alds[(t + 3) * 264 + cc] = f2bf(vv.w * sc + sh);
            }
        }
    }

    const float QSCALE = 0.0625f * 1.44269504088896f;   // (1/sqrt(256)) * log2(e)

    for (int oi = 0; oi < 12; ++oi) {
        int O0 = oi * 64;
        __syncthreads();   // protect Wlds (and, at oi=0, publish Alds)
        {
            const unsigned short* wb = wqkv_bf + (size_t)O0 * 256;
#pragma unroll
            for (int j = 0; j < 8; ++j) {
                int qq = tid + j * 256;
                int lo = qq >> 5, sc2 = qq & 31;
                stage16(wb + (size_t)lo * 256 + ((sc2 ^ (lo & 7)) * 8), &Wlds[qq * 8]);
            }
        }
        __syncthreads();   // drains vmcnt: W tile ready

        f32x4 acc[2];
        acc[0] = f32x4{0.f, 0.f, 0.f, 0.f};
        acc[1] = f32x4{0.f, 0.f, 0.f, 0.f};
#pragma unroll
        for (int kk = 0; kk < 8; ++kk) {
            bf16x8 afr = *(const bf16x8*)&Alds[(wm * 16 + l15) * 264 + kk * 32 + g * 8];
#pragma unroll
            for (int nf = 0; nf < 2; ++nf) {
                int lo = wn * 32 + nf * 16 + l15;
                bf16x8 bfr = *(const bf16x8*)&Wlds[lo * 256 + (((kk * 4 + g) ^ (lo & 7)) * 8)];
                acc[nf] = __builtin_amdgcn_mfma_f32_16x16x32_bf16(afr, bfr, acc[nf], 0, 0, 0);
            }
        }

#pragma unroll
        for (int nf = 0; nf < 2; ++nf) {
            int o = O0 + wn * 32 + nf * 16 + l15;
            float bias = bqkv[o];
#pragma unroll
            for (int r = 0; r < 4; ++r) {
                int t = T0 + wm * 16 + g * 4 + r;
                float val = acc[nf][r] + bias;
                if (O0 < 256) {
                    q[((size_t)b * N + t) * C + o] = f2bf(val * QSCALE);
                } else if (O0 < 512) {
                    kt[((size_t)b * N + t) * C + (o - 256)] = f2bf(val);
                } else {
                    int tp = (t & ~31) | ((g * 2 + wm) * 4 + r);
                    v[((size_t)b * C + (o - 512)) * N + tp] = f2bf(val);
                }
            }
        }
    }
}

// ---------------- Kernel 3: flash attention (shuffle-free steady softmax) ------
// As R11 (mrep=2, NSEG segs, 2 blocks/CU) but: per-iter softmax has ZERO
// cross-lane shuffles in the common path. Each lane accumulates lg[m] over its
// OWN 8 tokens; cross-g l-sum deferred to epilogue (2 shfls once). Cross-g max
// only on rare defer-trigger.
template<int NSEG>
__global__ __launch_bounds__(256, 2) void attn_k(
    const unsigned short* __restrict__ q, const unsigned short* __restrict__ kt,
    const unsigned short* __restrict__ v,
    unsigned short* __restrict__ P, float* __restrict__ ml)
{
    constexpr int NS  = N / NSEG;    // tokens per segment
    constexpr int NIT = NS / TS;     // tile iterations
    __shared__ unsigned short Klds[2][TS * 256];   // dbuf [tk][c-chunks^] 32KB
    __shared__ unsigned short Vlds[2][256 * TS];   // dbuf [c][tok-slots]  32KB

    int tid = threadIdx.x;
    int h  = blockIdx.y;          // KV segment
    int b  = blockIdx.z;
    int Q0 = blockIdx.x * 128;
    int lane = tid & 63;
    int lw = tid >> 6;            // wave = 32 Q rows
    int g = lane >> 4, l15 = lane & 15;

    bf16x8 qf[2][8];
#pragma unroll
    for (int m = 0; m < 2; ++m) {
        const unsigned short* qp = q + ((size_t)b * N + Q0 + lw * 32 + m * 16 + l15) * C + g * 8;
#pragma unroll
        for (int kc = 0; kc < 8; ++kc)
            qf[m][kc] = *(const bf16x8*)(qp + kc * 32);
    }

    f32x4 oacc[2][16];
#pragma unroll
    for (int m = 0; m < 2; ++m)
#pragma unroll
        for (int i = 0; i < 16; ++i) oacc[m][i] = f32x4{0.f, 0.f, 0.f, 0.f};
    float mrow[2] = {-1e30f, -1e30f};   // common across g (log2 domain)
    float lg[2]   = {0.f, 0.f};         // per-lane partial sum (own 8 toks/iter)

    const unsigned short* kb = kt + ((size_t)b * N + h * NS) * C;
    const unsigned short* vb = v + (size_t)b * C * N + h * NS;

#define STAGE(buf_, t_)                                                              \
    {                                                                                \
        const unsigned short* kbt = kb + (size_t)(t_) * TS * 256;                    \
        _Pragma("unroll")                                                            \
        for (int j = 0; j < 4; ++j) {                                                \
            int qq = tid + j * 256;                                                  \
            int tk = qq >> 5, sc = qq & 31;                                          \
            stage16(kbt + tk * 256 + ((sc ^ (tk & 7)) * 8), &Klds[buf_][qq * 8]);    \
        }                                                                            \
        _Pragma("unroll")                                                            \
        for (int j = 0; j < 4; ++j) {                                                \
            int qq = tid + j * 256;                                                  \
            int c = qq >> 2, sl = qq & 3;                                            \
            stage16(vb + (size_t)c * N + (t_) * TS + ((sl ^ ((c >> 1) & 3)) * 8),    \
                    &Vlds[buf_][qq * 8]);                                            \
        }                                                                            \
    }

    STAGE(0, 0);
    __syncthreads();

    for (int t = 0; t < NIT; ++t) {
        int cur = t & 1;
        if (t < NIT - 1) STAGE(cur ^ 1, t + 1);

        f32x4 st[2][2];
#pragma unroll
        for (int m = 0; m < 2; ++m)
#pragma unroll
            for (int ct = 0; ct < 2; ++ct) st[m][ct] = f32x4{0.f, 0.f, 0.f, 0.f};
        __builtin_amdgcn_s_setprio(1);
#pragma unroll
        for (int kc = 0; kc < 8; ++kc) {
#pragma unroll
            for (int ct = 0; ct < 2; ++ct) {
                int tk = ct * 16 + l15;
                int slot = (kc * 4 + g) ^ (tk & 7);
                bf16x8 kf = *(const bf16x8*)&Klds[cur][tk * 256 + slot * 8];
                st[0][ct] = __builtin_amdgcn_mfma_f32_16x16x32_bf16(kf, qf[0][kc], st[0][ct], 0, 0, 0);
                st[1][ct] = __builtin_amdgcn_mfma_f32_16x16x32_bf16(kf, qf[1][kc], st[1][ct], 0, 0, 0);
            }
        }
        __builtin_amdgcn_s_setprio(0);

        // lane-local max over own 8 toks (no shuffles)
        float mx[2];
#pragma unroll
        for (int m = 0; m < 2; ++m)
            mx[m] = fmaxf(fmaxf(fmaxf(st[m][0][0], st[m][0][1]), fmaxf(st[m][0][2], st[m][0][3])),
                          fmaxf(fmaxf(st[m][1][0], st[m][1][1]), fmaxf(st[m][1][2], st[m][1][3])));
        bool ok = (mx[0] - mrow[0] <= 8.f) & (mx[1] - mrow[1] <= 8.f);
        if (!__all(ok)) {
            // rare: establish common max across g, rescale O and lg
#pragma unroll
            for (int m = 0; m < 2; ++m) {
                float v0 = mx[m];
                v0 = fmaxf(v0, __shfl_xor(v0, 16));
                v0 = fmaxf(v0, __shfl_xor(v0, 32));
                float mn = fmaxf(mrow[m], v0);
                float alpha = exp2f(mrow[m] - mn);
                mrow[m] = mn;
                lg[m] *= alpha;
#pragma unroll
                for (int f = 0; f < 16; ++f)
#pragma unroll
                    for (int r = 0; r < 4; ++r) oacc[m][f][r] *= alpha;
            }
        }
        bf16x8 pf[2];
#pragma unroll
        for (int m = 0; m < 2; ++m) {
            float rs = 0.f;
#pragma unroll
            for (int ct = 0; ct < 2; ++ct)
#pragma unroll
                for (int r = 0; r < 4; ++r) {
                    float p = exp2f(st[m][ct][r] - mrow[m]);
                    st[m][ct][r] = p;
                    rs += p;
                }
            lg[m] += rs;   // lane-local; cross-g sum deferred to epilogue
            u32x4 pk;
            pk[0] = cvt_pk_bf16(st[m][0][0], st[m][0][1]);
            pk[1] = cvt_pk_bf16(st[m][0][2], st[m][0][3]);
            pk[2] = cvt_pk_bf16(st[m][1][0], st[m][1][1]);
            pk[3] = cvt_pk_bf16(st[m][1][2], st[m][1][3]);
            pf[m] = __builtin_bit_cast(bf16x8, pk);
        }

        __builtin_amdgcn_s_setprio(1);
#pragma unroll
        for (int cf = 0; cf < 16; ++cf) {
            int c = cf * 16 + l15;
            int vslot = g ^ ((c >> 1) & 3);
            bf16x8 vf = *(const bf16x8*)&Vlds[cur][c * TS + vslot * 8];
            oacc[0][cf] = __builtin_amdgcn_mfma_f32_16x16x32_bf16(vf, pf[0], oacc[0][cf], 0, 0, 0);
            oacc[1][cf] = __builtin_amdgcn_mfma_f32_16x16x32_bf16(vf, pf[1], oacc[1][cf], 0, 0, 0);
        }
        __builtin_amdgcn_s_setprio(0);
        __syncthreads();
    }

    // epilogue: cross-g l-sum (once), then write partials + m,l
    float lt[2];
#pragma unroll
    for (int m = 0; m < 2; ++m) {
        float v0 = lg[m];
        v0 += __shfl_xor(v0, 16);
        v0 += __shfl_xor(v0, 32);
        lt[m] = v0;
    }
#pragma unroll
    for (int m = 0; m < 2; ++m) {
        size_t tokid = (size_t)b * N + Q0 + lw * 32 + m * 16 + l15;
        if (g == 0) {
            ml[(size_t)(2 * h + 0) * (BB * N) + tokid] = mrow[m];
            ml[(size_t)(2 * h + 1) * (BB * N) + tokid] = lt[m];
        }
        unsigned short* pp = P + (size_t)h * BBNC + tokid * C;
#pragma unroll
        for (int cf = 0; cf < 16; ++cf) {
#pragma unroll
            for (int rp = 0; rp < 2; ++rp) {
                int c = cf * 16 + g * 4 + rp * 2;
                unsigned int pk2 = cvt_pk_bf16(oacc[m][cf][rp * 2 + 0], oacc[m][cf][rp * 2 + 1]);
                *(unsigned int*)&pp[c] = pk2;
            }
        }
    }
}

// ---------------- Kernel 4: out projection + combine (P read ONCE) ------------
template<int NSEG>
__global__ __launch_bounds__(256) void out_gemm_k(
    const unsigned short* __restrict__ P, const float* __restrict__ ml,
    const float* __restrict__ Wout, const float* __restrict__ bout,
    const float* __restrict__ x, float* __restrict__ out)
{
    __shared__ unsigned short Alds[256 * 40];   // Wout [co][32c] bf16, pad 40
    __shared__ unsigned short Blds[32 * 40];    // combined ao [t][32c]

    int tid = threadIdx.x;
    int b  = blockIdx.y;
    int T0 = blockIdx.x * 32;
    int lane = tid & 63;
    int w = tid >> 6;
    int g = lane >> 4, l15 = lane & 15;

    int tl = (tid >> 2) & 31;
    float cw[NSEG], cinv;
    {
        size_t tok = (size_t)b * N + T0 + tl;
        float ms[NSEG], ls[NSEG];
#pragma unroll
        for (int s = 0; s < NSEG; ++s) {
            ms[s] = ml[(size_t)(2 * s + 0) * (BB * N) + tok];
            ls[s] = ml[(size_t)(2 * s + 1) * (BB * N) + tok];
        }
        float M = ms[0];
#pragma unroll
        for (int s = 1; s < NSEG; ++s) M = fmaxf(M, ms[s]);
        float den = 0.f;
#pragma unroll
        for (int s = 0; s < NSEG; ++s) {
            cw[s] = exp2f(ms[s] - M);
            den += cw[s] * ls[s];
        }
        cinv = 1.f / den;
    }

    f32x4 acc[4][2];
#pragma unroll
    for (int i = 0; i < 4; ++i)
#pragma unroll
        for (int j = 0; j < 2; ++j) acc[i][j] = f32x4{0.f, 0.f, 0.f, 0.f};

    for (int c0 = 0; c0 < C; c0 += 32) {
        if (c0) __syncthreads();
        {
            const float4* wp = (const float4*)(Wout + (size_t)tid * C + c0);
            unsigned int wpk[16];
#pragma unroll
            for (int j = 0; j < 8; ++j) {
                float4 vv = wp[j];
                wpk[2 * j + 0] = cvt_pk_bf16(vv.x, vv.y);
                wpk[2 * j + 1] = cvt_pk_bf16(vv.z, vv.w);
            }
#pragma unroll
            for (int j = 0; j < 16; ++j)
                *(unsigned int*)&Alds[tid * 40 + j * 2] = wpk[j];
        }
        if (tid < 128) {
            int j = tid & 3;
            size_t base = ((size_t)b * N + T0 + tl) * C + c0 + j * 8;
            float val[8];
#pragma unroll
            for (int e = 0; e < 8; ++e) val[e] = 0.f;
#pragma unroll
            for (int s = 0; s < NSEG; ++s) {
                bf16x8 p = *(const bf16x8*)(P + (size_t)s * BBNC + base);
                float wgt = cw[s];
#pragma unroll
                for (int e = 0; e < 8; ++e) val[e] += wgt * bf2f((unsigned short)p[e]);
            }
            unsigned int opk[4];
#pragma unroll
            for (int jj = 0; jj < 4; ++jj)
                opk[jj] = cvt_pk_bf16(val[2 * jj] * cinv, val[2 * jj + 1] * cinv);
            *(u32x4*)&Blds[tl * 40 + j * 8] = *(u32x4*)opk;
        }
        __syncthreads();

        bf16x8 afr[4];
#pragma unroll
        for (int mf = 0; mf < 4; ++mf)
            afr[mf] = *(const bf16x8*)&Alds[(w * 64 + mf * 16 + l15) * 40 + g * 8];
#pragma unroll
        for (int tf = 0; tf < 2; ++tf) {
            bf16x8 bfr = *(const bf16x8*)&Blds[(tf * 16 + l15) * 40 + g * 8];
#pragma unroll
            for (int mf = 0; mf < 4; ++mf)
                acc[mf][tf] = __builtin_amdgcn_mfma_f32_16x16x32_bf16(afr[mf], bfr, acc[mf][tf], 0, 0, 0);
        }
    }

#pragma unroll
    for (int mf = 0; mf < 4; ++mf) {
#pragma unroll
        for (int tf = 0; tf < 2; ++tf) {
            int t = T0 + tf * 16 + l15;
#pragma unroll
            for (int r = 0; r < 4; ++r) {
                int co = w * 64 + mf * 16 + g * 4 + r;
                size_t oidx = ((size_t)b * C + co) * N + t;
                out[oidx] = acc[mf][tf][r] + bout[co] + x[oidx];
            }
        }
    }
}

extern "C" void kernel_launch(void* const* d_in, const int* in_sizes, int n_in,
                              void* d_out, int out_size, void* d_ws, size_t ws_size,
                              hipStream_t stream) {
    const float* x     = (const float*)d_in[0];
    const float* Wqkv  = (const float*)d_in[1];
    const float* bqkv  = (const float*)d_in[2];
    const float* Wout  = (const float*)d_in[3];
    const float* bout  = (const float*)d_in[4];
    const float* gamma = (const float*)d_in[5];
    const float* beta  = (const float*)d_in[6];
    float* out = (float*)d_out;

    char* ws = (char*)d_ws;
    float* scale = (float*)ws;
    float* shift = (float*)(ws + 1024);
    unsigned short* q  = (unsigned short*)(ws + 4096);
    unsigned short* kt = q  + BBNC;
    unsigned short* v  = kt + BBNC;
    unsigned short* P  = v  + BBNC;
    // Wqkv-bf16 aliases P: written first, consumed by qkv_gemm, then attn overwrites P.
    unsigned short* wqkv_bf = P;

    size_t need4 = 4096 + 7 * BBNC * 2 + (size_t)8 * BB * N * 4;

    bn_stats_k<<<dim3(C + 96), dim3(256), 0, stream>>>(x, gamma, beta, scale, shift, Wqkv, wqkv_bf);
    qkv_gemm_k<<<dim3(N / 32, BB), dim3(256), 0, stream>>>(x, wqkv_bf, bqkv, scale, shift, q, kt, v);

    if (ws_size >= need4) {
        float* ml = (float*)(P + 4 * BBNC);
        attn_k<4><<<dim3(N / 128, 4, BB), dim3(256), 0, stream>>>(q, kt, v, P, ml);
        out_gemm_k<4><<<dim3(N / 32, BB), dim3(256), 0, stream>>>(P, ml, Wout, bout, x, out);
    } else {
        float* ml = (float*)(P + 2 * BBNC);
        attn_k<2><<<dim3(N / 128, 2, BB), dim3(256), 0, stream>>>(q, kt, v, P, ml);
        out_gemm_k<2><<<dim3(N / 32, BB), dim3(256), 0, stream>>>(P, ml, Wout, bout, x, out);
    }
}